// Round 6
// baseline (541.000 us; speedup 1.0000x reference)
//
#include <hip/hip_runtime.h>
#include <hip/hip_bf16.h>
#include <math.h>

typedef __bf16 bf16x8 __attribute__((ext_vector_type(8)));
typedef float f32x4 __attribute__((ext_vector_type(4)));

constexpr int HID = 1024;
constexpr int NHEAD = 16;
constexpr int NKV = 4;
constexpr int HDIM = 64;
constexpr int NEXP = 16;
constexpr int FFD = 1024;
constexpr int NB = 2;
constexpr int SEQ = 1024;
constexpr int TOK = NB * SEQ;
constexpr int QKV_N = NHEAD * HDIM + 2 * NKV * HDIM;  // 1536
constexpr float RMS_EPS = 1e-6f;
constexpr int LDP = 40;          // padded LDS row stride (bf16 elems)
constexpr int PL = 64 * LDP;     // one 64-row LDS plane
constexpr int MAXBLK = 2 * TOK / 64 + NEXP;  // 80: max MoE m-block slots

// Raw barrier WITHOUT the __syncthreads vmcnt(0) drain. hipcc emits
// "s_waitcnt vmcnt(0) lgkmcnt(0)" before s_barrier for __syncthreads
// (workgroup fence semantics) — that drain force-completes the in-flight
// register prefetch at EVERY k-step barrier, making prefetch depth,
// occupancy and grid shape all irrelevant (rounds 0-5 invariance).
// lgkmcnt(0) keeps LDS producer->consumer ordering; global loads stay
// in flight. Compiler still emits counted vmcnt(N) waits before the
// staged regs are consumed (dependency-driven), so no manual counting.
// These GEMMs have no intra-kernel global communication -> safe.
#define BAR() do { \
  asm volatile("s_waitcnt lgkmcnt(0)" ::: "memory"); \
  __builtin_amdgcn_s_barrier(); \
  __builtin_amdgcn_sched_barrier(0); \
} while (0)

// x = h1 + h2 with h2 ~ eps*x (residual sub exact). Double-split: product
// error ~eps^2 ~1.5e-5 relative — 3 orders below the MoE bf16 error floor
// (absmax 0.015625 set by the single-bf16 MoE path).
__device__ __forceinline__ void split2(float x, __bf16& h1, __bf16& h2) {
  h1 = (__bf16)x;
  h2 = (__bf16)(x - (float)h1);
}

// 3-combination double-split MFMA step: a1b1 + a1b2 + a2b1, error ~eps^2.
// Planes in LDS: A1 @0, A2 @PL, B1 @2PL, B2 @3PL.
__device__ __forceinline__ void mfma_step3(const __bf16* sm, int wr, int wc,
                                           int lm, int lq, f32x4 (&acc)[2][2]) {
  int ao0 = (wr + lm) * LDP + lq * 8, ao1 = (wr + 16 + lm) * LDP + lq * 8;
  int bo0 = (wc + lm) * LDP + lq * 8, bo1 = (wc + 16 + lm) * LDP + lq * 8;
  bf16x8 a10 = *(const bf16x8*)(sm + ao0),          a11 = *(const bf16x8*)(sm + ao1);
  bf16x8 a20 = *(const bf16x8*)(sm + PL + ao0),     a21 = *(const bf16x8*)(sm + PL + ao1);
  bf16x8 b10 = *(const bf16x8*)(sm + 2 * PL + bo0), b11 = *(const bf16x8*)(sm + 2 * PL + bo1);
  bf16x8 b20 = *(const bf16x8*)(sm + 3 * PL + bo0), b21 = *(const bf16x8*)(sm + 3 * PL + bo1);
#define MF(A, B, i, j) acc[i][j] = __builtin_amdgcn_mfma_f32_16x16x32_bf16(A, B, acc[i][j], 0, 0, 0)
  MF(a10, b10, 0, 0); MF(a10, b11, 0, 1); MF(a11, b10, 1, 0); MF(a11, b11, 1, 1);
  MF(a10, b20, 0, 0); MF(a10, b21, 0, 1); MF(a11, b20, 1, 0); MF(a11, b21, 1, 1);
  MF(a20, b10, 0, 0); MF(a20, b11, 0, 1); MF(a21, b10, 1, 0); MF(a21, b11, 1, 1);
#undef MF
}

__device__ __forceinline__ void cvt8(__bf16* dst, float4 f0, float4 f1) {
  __bf16 tmp[8] __attribute__((aligned(16))) = {
      (__bf16)f0.x, (__bf16)f0.y, (__bf16)f0.z, (__bf16)f0.w,
      (__bf16)f1.x, (__bf16)f1.y, (__bf16)f1.z, (__bf16)f1.w};
  *(int4*)dst = *(const int4*)tmp;
}

// ---------------- pre/post small kernels ----------------

__global__ __launch_bounds__(256) void split2_kernel(
    const float* __restrict__ src, __bf16* __restrict__ p1,
    __bf16* __restrict__ p2, int n) {
  int i = (blockIdx.x * 256 + threadIdx.x) * 4;
  if (i >= n) return;
  float4 v = *(const float4*)(src + i);
  __bf16 t1[4] __attribute__((aligned(8))), t2[4] __attribute__((aligned(8)));
  split2(v.x, t1[0], t2[0]);
  split2(v.y, t1[1], t2[1]);
  split2(v.z, t1[2], t2[2]);
  split2(v.w, t1[3], t2[3]);
  *(int2*)(p1 + i) = *(const int2*)t1;
  *(int2*)(p2 + i) = *(const int2*)t2;
}

__global__ __launch_bounds__(256) void rmsnorm_split2_kernel(
    const float* __restrict__ x, const float* __restrict__ w,
    __bf16* __restrict__ p1, __bf16* __restrict__ p2) {
  int row = blockIdx.x;
  const float* xr = x + (size_t)row * HID;
  float4 v = ((const float4*)xr)[threadIdx.x];
  float ss = v.x * v.x + v.y * v.y + v.z * v.z + v.w * v.w;
  for (int off = 32; off; off >>= 1) ss += __shfl_xor(ss, off);
  __shared__ float red[4];
  int lane = threadIdx.x & 63, wid = threadIdx.x >> 6;
  if (lane == 0) red[wid] = ss;
  __syncthreads();
  float tot = red[0] + red[1] + red[2] + red[3];
  float scale = rsqrtf(tot / (float)HID + RMS_EPS);
  float4 wv = ((const float4*)w)[threadIdx.x];
  float o[4] = {v.x * scale * wv.x, v.y * scale * wv.y,
                v.z * scale * wv.z, v.w * scale * wv.w};
  __bf16 t1[4] __attribute__((aligned(8))), t2[4] __attribute__((aligned(8)));
#pragma unroll
  for (int i = 0; i < 4; i++) split2(o[i], t1[i], t2[i]);
  size_t idx = (size_t)row * HID + threadIdx.x * 4;
  *(int2*)(p1 + idx) = *(const int2*)t1;
  *(int2*)(p2 + idx) = *(const int2*)t2;
}

__global__ __launch_bounds__(256) void rmsnorm_dual_kernel(
    const float* __restrict__ x, const float* __restrict__ w,
    float* __restrict__ outf, __bf16* __restrict__ outb) {
  int row = blockIdx.x;
  const float* xr = x + (size_t)row * HID;
  float4 v = ((const float4*)xr)[threadIdx.x];
  float ss = v.x * v.x + v.y * v.y + v.z * v.z + v.w * v.w;
  for (int off = 32; off; off >>= 1) ss += __shfl_xor(ss, off);
  __shared__ float red[4];
  int lane = threadIdx.x & 63, wid = threadIdx.x >> 6;
  if (lane == 0) red[wid] = ss;
  __syncthreads();
  float tot = red[0] + red[1] + red[2] + red[3];
  float scale = rsqrtf(tot / (float)HID + RMS_EPS);
  float4 wv = ((const float4*)w)[threadIdx.x];
  float o[4] = {v.x * scale * wv.x, v.y * scale * wv.y,
                v.z * scale * wv.z, v.w * scale * wv.w};
  size_t idx = (size_t)row * HID + threadIdx.x * 4;
  *(float4*)(outf + idx) = *(const float4*)o;
  __bf16 tb[4] __attribute__((aligned(8)));
#pragma unroll
  for (int i = 0; i < 4; i++) tb[i] = (__bf16)o[i];
  *(int2*)(outb + idx) = *(const int2*)tb;
}

__global__ __launch_bounds__(256) void rope_split_kernel(
    const float* __restrict__ qkv, const int* __restrict__ pos_ids,
    const float* __restrict__ qn_w, const float* __restrict__ kn_w,
    __bf16* __restrict__ qp1, __bf16* __restrict__ qp2,
    __bf16* __restrict__ kp1, __bf16* __restrict__ kp2,
    __bf16* __restrict__ vp1, __bf16* __restrict__ vp2) {
  int t = blockIdx.x;
  int b = t >> 10, s = t & 1023;
  int lane = threadIdx.x & 63, w = threadIdx.x >> 6;
  float pos = (float)pos_ids[t];
  int fi = lane & 31;
  float inv = powf(10000.0f, -((float)(2 * fi)) / 64.0f);
  float cs = cosf(pos * inv), sn = sinf(pos * inv);
  for (int i = 0; i < 6; i++) {
    int hh = w + 4 * i;  // 0-15 q heads, 16-19 k heads, 20-23 v heads
    float val = qkv[(size_t)t * QKV_N + hh * 64 + lane];
    __bf16 h1, h2;
    if (hh < 20) {
      float ss = val * val;
      for (int off = 32; off; off >>= 1) ss += __shfl_xor(ss, off);
      float scale = rsqrtf(ss / 64.0f + RMS_EPS);
      float wgt = (hh < 16) ? qn_w[lane] : kn_w[lane];
      val = val * scale * wgt;
      float partner = __shfl_xor(val, 32);
      float rot = (lane < 32) ? -partner : partner;
      val = val * cs + rot * sn;
      split2(val, h1, h2);
      if (hh < 16) {
        size_t idx = (((size_t)b * NHEAD + hh) * SEQ + s) * HDIM + lane;
        qp1[idx] = h1; qp2[idx] = h2;
      } else {
        size_t idx = (((size_t)b * NKV + (hh - 16)) * SEQ + s) * HDIM + lane;
        kp1[idx] = h1; kp2[idx] = h2;
      }
    } else {
      split2(val, h1, h2);
      size_t idx = (((size_t)b * NKV + (hh - 20)) * HDIM + lane) * SEQ + s;
      vp1[idx] = h1; vp2[idx] = h2;
    }
  }
}

// scores land as a single fp32 plane; softmax emits 2 bf16 planes for PV.
__global__ __launch_bounds__(256) void softmax2_kernel(
    const float* __restrict__ sf,
    __bf16* __restrict__ p1, __bf16* __restrict__ p2) {
  size_t roff = (size_t)blockIdx.x * SEQ;
  int tid = threadIdx.x;
  float4 v4 = *(const float4*)(sf + roff + tid * 4);
  float v[4] = {v4.x, v4.y, v4.z, v4.w};
  float mx = fmaxf(fmaxf(v[0], v[1]), fmaxf(v[2], v[3]));
  for (int off = 32; off; off >>= 1) mx = fmaxf(mx, __shfl_xor(mx, off));
  __shared__ float red[4], red2[4];
  int lane = tid & 63, wid = tid >> 6;
  if (lane == 0) red[wid] = mx;
  __syncthreads();
  mx = fmaxf(fmaxf(red[0], red[1]), fmaxf(red[2], red[3]));
  float e[4], sum = 0.f;
#pragma unroll
  for (int i = 0; i < 4; i++) { e[i] = expf(v[i] - mx); sum += e[i]; }
  for (int off = 32; off; off >>= 1) sum += __shfl_xor(sum, off);
  if (lane == 0) red2[wid] = sum;
  __syncthreads();
  sum = red2[0] + red2[1] + red2[2] + red2[3];
  float invs = 1.0f / sum;
  __bf16 t1[4] __attribute__((aligned(8))), t2[4] __attribute__((aligned(8)));
#pragma unroll
  for (int i = 0; i < 4; i++) split2(e[i] * invs, t1[i], t2[i]);
  *(int2*)(p1 + roff + tid * 4) = *(const int2*)t1;
  *(int2*)(p2 + roff + tid * 4) = *(const int2*)t2;
}

// ------------- double-split GEMMs (64x64 tile, BK=32) -------------
// 2-deep register prefetch (named sets A/B, unroll-2 — rule #20) + LDS dbuf,
// 1 raw barrier/step (BAR: no vmcnt drain -> prefetch survives barriers).

__global__ __launch_bounds__(256) void gemm_qkv4(
    const __bf16* __restrict__ a1, const __bf16* __restrict__ a2,
    const __bf16* __restrict__ b1, const __bf16* __restrict__ b2,
    float* __restrict__ qkv) {
  int m0 = blockIdx.x * 64, n0 = blockIdx.y * 64;
  __shared__ __bf16 sm[2][4 * PL];  // 40 KB
  int tid = threadIdx.x, r = tid >> 2, c8 = (tid & 3) * 8;
  size_t aoff = (size_t)(m0 + r) * HID + c8, boff = (size_t)(n0 + r) * HID + c8;
  f32x4 acc[2][2] = {};
  int lane = tid & 63, wid = tid >> 6;
  int wr = (wid >> 1) * 32, wc = (wid & 1) * 32, lq = lane >> 4, lm = lane & 15;
  int sidx = r * LDP + c8;
  int4 rA1, rA2, rA3, rA4, rB1, rB2, rB3, rB4;
  auto preloadA = [&](int k0) {
    rA1 = *(const int4*)(a1 + aoff + k0); rA2 = *(const int4*)(a2 + aoff + k0);
    rA3 = *(const int4*)(b1 + boff + k0); rA4 = *(const int4*)(b2 + boff + k0);
  };
  auto preloadB = [&](int k0) {
    rB1 = *(const int4*)(a1 + aoff + k0); rB2 = *(const int4*)(a2 + aoff + k0);
    rB3 = *(const int4*)(b1 + boff + k0); rB4 = *(const int4*)(b2 + boff + k0);
  };
  auto stageA = [&](int p) {
    *(int4*)&sm[p][0 * PL + sidx] = rA1; *(int4*)&sm[p][1 * PL + sidx] = rA2;
    *(int4*)&sm[p][2 * PL + sidx] = rA3; *(int4*)&sm[p][3 * PL + sidx] = rA4;
  };
  auto stageB = [&](int p) {
    *(int4*)&sm[p][0 * PL + sidx] = rB1; *(int4*)&sm[p][1 * PL + sidx] = rB2;
    *(int4*)&sm[p][2 * PL + sidx] = rB3; *(int4*)&sm[p][3 * PL + sidx] = rB4;
  };
  preloadA(0); stageA(0);
  preloadA(32); preloadB(64);
  BAR();
  int p = 0;
  for (int k0 = 0; k0 < HID; k0 += 64) {
    if (k0 + 32 < HID) stageA(p ^ 1);
    if (k0 + 96 < HID) preloadA(k0 + 96);
    mfma_step3(sm[p], wr, wc, lm, lq, acc);
    BAR(); p ^= 1;
    if (k0 + 64 < HID) stageB(p ^ 1);
    if (k0 + 128 < HID) preloadB(k0 + 128);
    mfma_step3(sm[p], wr, wc, lm, lq, acc);
    BAR(); p ^= 1;
  }
#pragma unroll
  for (int mt = 0; mt < 2; mt++)
#pragma unroll
    for (int nt = 0; nt < 2; nt++)
#pragma unroll
      for (int i = 0; i < 4; i++) {
        int gm = m0 + wr + mt * 16 + lq * 4 + i;
        int gc = n0 + wc + nt * 16 + lm;
        qkv[(size_t)gm * QKV_N + gc] = acc[mt][nt][i];
      }
}

__global__ __launch_bounds__(256) void gemm_scores4(
    const __bf16* __restrict__ qp1, const __bf16* __restrict__ qp2,
    const __bf16* __restrict__ kp1, const __bf16* __restrict__ kp2,
    float* __restrict__ sf, int b, int h0) {
  int hz = blockIdx.z, h = h0 + hz;
  int m0 = blockIdx.x * 64, n0 = blockIdx.y * 64;
  size_t qbase = ((size_t)(b * NHEAD + h)) * SEQ * HDIM;
  size_t kbase = ((size_t)(b * NKV + (h >> 2))) * SEQ * HDIM;
  __shared__ __bf16 sm[4 * PL];
  int tid = threadIdx.x, r = tid >> 2, c8 = (tid & 3) * 8;
  size_t aoff = qbase + (size_t)(m0 + r) * HDIM + c8;
  size_t boff = kbase + (size_t)(n0 + r) * HDIM + c8;
  f32x4 acc[2][2] = {};
  int lane = tid & 63, wid = tid >> 6;
  int wr = (wid >> 1) * 32, wc = (wid & 1) * 32, lq = lane >> 4, lm = lane & 15;
  int sidx = r * LDP + c8;
  int4 ra1, ra2, rb1, rb2;
  auto preload = [&](int k0) {
    ra1 = *(const int4*)(qp1 + aoff + k0);
    ra2 = *(const int4*)(qp2 + aoff + k0);
    rb1 = *(const int4*)(kp1 + boff + k0);
    rb2 = *(const int4*)(kp2 + boff + k0);
  };
  auto stage = [&]() {
    *(int4*)&sm[0 * PL + sidx] = ra1;
    *(int4*)&sm[1 * PL + sidx] = ra2;
    *(int4*)&sm[2 * PL + sidx] = rb1;
    *(int4*)&sm[3 * PL + sidx] = rb2;
  };
  preload(0); stage();
  for (int k0 = 0; k0 < HDIM; k0 += 32) {
    BAR();
    if (k0 + 32 < HDIM) preload(k0 + 32);
    mfma_step3(sm, wr, wc, lm, lq, acc);
    BAR();
    if (k0 + 32 < HDIM) stage();
  }
#pragma unroll
  for (int mt = 0; mt < 2; mt++)
#pragma unroll
    for (int nt = 0; nt < 2; nt++)
#pragma unroll
      for (int i = 0; i < 4; i++) {
        int gm = m0 + wr + mt * 16 + lq * 4 + i;
        int gc = n0 + wc + nt * 16 + lm;
        size_t idx = ((size_t)hz * SEQ + gm) * SEQ + gc;
        sf[idx] = acc[mt][nt][i] * 0.125f;
      }
}

__global__ __launch_bounds__(256) void gemm_pv4(
    const __bf16* __restrict__ s1, const __bf16* __restrict__ s2,
    const __bf16* __restrict__ vp1, const __bf16* __restrict__ vp2,
    __bf16* __restrict__ o1, __bf16* __restrict__ o2,
    int b, int h0) {
  int hz = blockIdx.z, h = h0 + hz;
  int m0 = blockIdx.x * 64;
  size_t pbase = (size_t)hz * SEQ * SEQ;
  size_t vbase = ((size_t)(b * NKV + (h >> 2))) * HDIM * SEQ;
  __shared__ __bf16 sm[2][4 * PL];  // 40 KB
  int tid = threadIdx.x, r = tid >> 2, c8 = (tid & 3) * 8;
  size_t aoff = pbase + (size_t)(m0 + r) * SEQ + c8;
  size_t boff = vbase + (size_t)r * SEQ + c8;
  f32x4 acc[2][2] = {};
  int lane = tid & 63, wid = tid >> 6;
  int wr = (wid >> 1) * 32, wc = (wid & 1) * 32, lq = lane >> 4, lm = lane & 15;
  int sidx = r * LDP + c8;
  int4 rA1, rA2, rA3, rA4, rB1, rB2, rB3, rB4;
  auto preloadA = [&](int k0) {
    rA1 = *(const int4*)(s1 + aoff + k0);  rA2 = *(const int4*)(s2 + aoff + k0);
    rA3 = *(const int4*)(vp1 + boff + k0); rA4 = *(const int4*)(vp2 + boff + k0);
  };
  auto preloadB = [&](int k0) {
    rB1 = *(const int4*)(s1 + aoff + k0);  rB2 = *(const int4*)(s2 + aoff + k0);
    rB3 = *(const int4*)(vp1 + boff + k0); rB4 = *(const int4*)(vp2 + boff + k0);
  };
  auto stageA = [&](int p) {
    *(int4*)&sm[p][0 * PL + sidx] = rA1; *(int4*)&sm[p][1 * PL + sidx] = rA2;
    *(int4*)&sm[p][2 * PL + sidx] = rA3; *(int4*)&sm[p][3 * PL + sidx] = rA4;
  };
  auto stageB = [&](int p) {
    *(int4*)&sm[p][0 * PL + sidx] = rB1; *(int4*)&sm[p][1 * PL + sidx] = rB2;
    *(int4*)&sm[p][2 * PL + sidx] = rB3; *(int4*)&sm[p][3 * PL + sidx] = rB4;
  };
  preloadA(0); stageA(0);
  preloadA(32); preloadB(64);
  BAR();
  int p = 0;
  for (int k0 = 0; k0 < SEQ; k0 += 64) {
    if (k0 + 32 < SEQ) stageA(p ^ 1);
    if (k0 + 96 < SEQ) preloadA(k0 + 96);
    mfma_step3(sm[p], wr, wc, lm, lq, acc);
    BAR(); p ^= 1;
    if (k0 + 64 < SEQ) stageB(p ^ 1);
    if (k0 + 128 < SEQ) preloadB(k0 + 128);
    mfma_step3(sm[p], wr, wc, lm, lq, acc);
    BAR(); p ^= 1;
  }
#pragma unroll
  for (int mt = 0; mt < 2; mt++)
#pragma unroll
    for (int nt = 0; nt < 2; nt++)
#pragma unroll
      for (int i = 0; i < 4; i++) {
        int gm = m0 + wr + mt * 16 + lq * 4 + i;
        int gc = wc + nt * 16 + lm;
        size_t idx = ((size_t)(b * SEQ + gm)) * HID + h * 64 + gc;
        __bf16 h1_, h2_;
        split2(acc[mt][nt][i], h1_, h2_);
        o1[idx] = h1_; o2[idx] = h2_;
      }
}

__global__ __launch_bounds__(256) void gemm_oproj4(
    const __bf16* __restrict__ a1, const __bf16* __restrict__ a2,
    const __bf16* __restrict__ b1, const __bf16* __restrict__ b2,
    const float* __restrict__ hidden, float* __restrict__ x1, float* __restrict__ outp) {
  int m0 = blockIdx.x * 64, n0 = blockIdx.y * 64;
  __shared__ __bf16 sm[2][4 * PL];  // 40 KB
  int tid = threadIdx.x, r = tid >> 2, c8 = (tid & 3) * 8;
  size_t aoff = (size_t)(m0 + r) * HID + c8, boff = (size_t)(n0 + r) * HID + c8;
  f32x4 acc[2][2] = {};
  int lane = tid & 63, wid = tid >> 6;
  int wr = (wid >> 1) * 32, wc = (wid & 1) * 32, lq = lane >> 4, lm = lane & 15;
  int sidx = r * LDP + c8;
  int4 rA1, rA2, rA3, rA4, rB1, rB2, rB3, rB4;
  auto preloadA = [&](int k0) {
    rA1 = *(const int4*)(a1 + aoff + k0); rA2 = *(const int4*)(a2 + aoff + k0);
    rA3 = *(const int4*)(b1 + boff + k0); rA4 = *(const int4*)(b2 + boff + k0);
  };
  auto preloadB = [&](int k0) {
    rB1 = *(const int4*)(a1 + aoff + k0); rB2 = *(const int4*)(a2 + aoff + k0);
    rB3 = *(const int4*)(b1 + boff + k0); rB4 = *(const int4*)(b2 + boff + k0);
  };
  auto stageA = [&](int p) {
    *(int4*)&sm[p][0 * PL + sidx] = rA1; *(int4*)&sm[p][1 * PL + sidx] = rA2;
    *(int4*)&sm[p][2 * PL + sidx] = rA3; *(int4*)&sm[p][3 * PL + sidx] = rA4;
  };
  auto stageB = [&](int p) {
    *(int4*)&sm[p][0 * PL + sidx] = rB1; *(int4*)&sm[p][1 * PL + sidx] = rB2;
    *(int4*)&sm[p][2 * PL + sidx] = rB3; *(int4*)&sm[p][3 * PL + sidx] = rB4;
  };
  preloadA(0); stageA(0);
  preloadA(32); preloadB(64);
  BAR();
  int p = 0;
  for (int k0 = 0; k0 < HID; k0 += 64) {
    if (k0 + 32 < HID) stageA(p ^ 1);
    if (k0 + 96 < HID) preloadA(k0 + 96);
    mfma_step3(sm[p], wr, wc, lm, lq, acc);
    BAR(); p ^= 1;
    if (k0 + 64 < HID) stageB(p ^ 1);
    if (k0 + 128 < HID) preloadB(k0 + 128);
    mfma_step3(sm[p], wr, wc, lm, lq, acc);
    BAR(); p ^= 1;
  }
#pragma unroll
  for (int mt = 0; mt < 2; mt++)
#pragma unroll
    for (int nt = 0; nt < 2; nt++)
#pragma unroll
      for (int i = 0; i < 4; i++) {
        int gm = m0 + wr + mt * 16 + lq * 4 + i;
        int gc = n0 + wc + nt * 16 + lm;
        size_t idx = (size_t)gm * HID + gc;
        float val = hidden[idx] + acc[mt][nt][i];
        x1[idx] = val;
        outp[idx] = val;
      }
}

// ---------------- MoE ----------------

__global__ void zero_cnt_kernel(int* cnt) {
  if (threadIdx.x < NEXP) cnt[threadIdx.x] = 0;
}

__global__ __launch_bounds__(64) void gating_kernel(
    const float* __restrict__ h2f, const float* __restrict__ gw,
    float* __restrict__ logits_out, int* __restrict__ cnt,
    int* __restrict__ list, float* __restrict__ wt) {
  int t = blockIdx.x;
  int lane = threadIdx.x;
  const float* xr = h2f + (size_t)t * HID;
  float part[NEXP] = {};
  for (int k = lane; k < HID; k += 64) {
    float xv = xr[k];
#pragma unroll
    for (int e = 0; e < NEXP; e++) part[e] += xv * gw[e * HID + k];
  }
#pragma unroll
  for (int e = 0; e < NEXP; e++)
    for (int off = 32; off; off >>= 1) part[e] += __shfl_xor(part[e], off);
  if (lane < NEXP) logits_out[(size_t)t * NEXP + lane] = part[lane];
  float mx = part[0];
#pragma unroll
  for (int e = 1; e < NEXP; e++) mx = fmaxf(mx, part[e]);
  float pe[NEXP];
#pragma unroll
  for (int e = 0; e < NEXP; e++) pe[e] = expf(part[e] - mx);
  int e0 = 0; float p0 = pe[0];
#pragma unroll
  for (int e = 1; e < NEXP; e++) if (pe[e] > p0) { p0 = pe[e]; e0 = e; }
  int e1 = -1; float p1 = -1.f;
#pragma unroll
  for (int e = 0; e < NEXP; e++) if (e != e0 && pe[e] > p1) { p1 = pe[e]; e1 = e; }
  float wsum = p0 + p1;
  if (lane == 0) {
    int pos0 = atomicAdd(&cnt[e0], 1);
    list[e0 * TOK + pos0] = t;
    wt[e0 * TOK + pos0] = p0 / wsum;
    int pos1 = atomicAdd(&cnt[e1], 1);
    list[e1 * TOK + pos1] = t;
    wt[e1 * TOK + pos1] = p1 / wsum;
  }
}

// scan + dense block table (round-5: keeps all-CU coverage; kept).
__global__ void scan_kernel(const int* __restrict__ cnt, int* __restrict__ base,
                            int* __restrict__ btab, int* __restrict__ nblk) {
  if (threadIdx.x == 0 && blockIdx.x == 0) {
    int acc = 0, nb = 0;
    for (int e = 0; e < NEXP; e++) {
      base[e] = acc; acc += cnt[e];
      for (int m0 = 0; m0 < cnt[e]; m0 += 64) {
        btab[2 * nb] = e; btab[2 * nb + 1] = m0; nb++;
      }
    }
    base[NEXP] = acc;
    *nblk = nb;
  }
}

// fused gate+up, 64x64 tile, BK=32, LDS dbuf + 2-deep reg prefetch,
// 1 raw barrier/iter (no vmcnt drain). grid (FFD/64, MAXBLK) over dense btab.
__global__ __launch_bounds__(256) void gemm_gateup3(
    const __bf16* __restrict__ h2, const float* __restrict__ w_gate,
    const float* __restrict__ w_up, const int* __restrict__ cnt,
    const int* __restrict__ base, const int* __restrict__ list,
    const int* __restrict__ btab, const int* __restrict__ nblk,
    __bf16* __restrict__ aws) {
  int slot = blockIdx.y;
  if (slot >= *nblk) return;
  int e = btab[2 * slot], m0 = btab[2 * slot + 1];
  int ce = cnt[e];
  int n0 = blockIdx.x * 64;
  int be = base[e];
  __shared__ __bf16 As[2][PL], Bg[2][PL], Bu[2][PL];  // 30 KB
  int tid = threadIdx.x, r = tid >> 2, c8 = (tid & 3) * 8;
  int ridx = m0 + r; if (ridx >= ce) ridx = ce - 1;
  const __bf16* arow = h2 + (size_t)list[e * TOK + ridx] * HID + c8;
  const float* bgrow = w_gate + ((size_t)e * FFD + n0 + r) * HID + c8;
  const float* burow = w_up + ((size_t)e * FFD + n0 + r) * HID + c8;
  int lane = tid & 63, wid = tid >> 6;
  int wr = (wid >> 1) * 32, wc = (wid & 1) * 32, lq = lane >> 4, lm = lane & 15;
  int sidx = r * LDP + c8;
  f32x4 ag[2][2] = {}, au[2][2] = {};
  int4 raA, raB; float4 rgA0, rgA1, ruA0, ruA1, rgB0, rgB1, ruB0, ruB1;
  auto preloadA = [&](int k0) {
    raA = *(const int4*)(arow + k0);
    rgA0 = *(const float4*)(bgrow + k0); rgA1 = *(const float4*)(bgrow + k0 + 4);
    ruA0 = *(const float4*)(burow + k0); ruA1 = *(const float4*)(burow + k0 + 4);
  };
  auto preloadB = [&](int k0) {
    raB = *(const int4*)(arow + k0);
    rgB0 = *(const float4*)(bgrow + k0); rgB1 = *(const float4*)(bgrow + k0 + 4);
    ruB0 = *(const float4*)(burow + k0); ruB1 = *(const float4*)(burow + k0 + 4);
  };
  auto stageA = [&](int p) {
    *(int4*)&As[p][sidx] = raA;
    cvt8(&Bg[p][sidx], rgA0, rgA1);
    cvt8(&Bu[p][sidx], ruA0, ruA1);
  };
  auto stageB = [&](int p) {
    *(int4*)&As[p][sidx] = raB;
    cvt8(&Bg[p][sidx], rgB0, rgB1);
    cvt8(&Bu[p][sidx], ruB0, ruB1);
  };
  auto compute = [&](int p) {
    bf16x8 a0 = *(const bf16x8*)(&As[p][(wr + lm) * LDP + lq * 8]);
    bf16x8 a1 = *(const bf16x8*)(&As[p][(wr + 16 + lm) * LDP + lq * 8]);
    bf16x8 g0 = *(const bf16x8*)(&Bg[p][(wc + lm) * LDP + lq * 8]);
    bf16x8 g1 = *(const bf16x8*)(&Bg[p][(wc + 16 + lm) * LDP + lq * 8]);
    bf16x8 u0 = *(const bf16x8*)(&Bu[p][(wc + lm) * LDP + lq * 8]);
    bf16x8 u1 = *(const bf16x8*)(&Bu[p][(wc + 16 + lm) * LDP + lq * 8]);
    ag[0][0] = __builtin_amdgcn_mfma_f32_16x16x32_bf16(a0, g0, ag[0][0], 0, 0, 0);
    ag[0][1] = __builtin_amdgcn_mfma_f32_16x16x32_bf16(a0, g1, ag[0][1], 0, 0, 0);
    ag[1][0] = __builtin_amdgcn_mfma_f32_16x16x32_bf16(a1, g0, ag[1][0], 0, 0, 0);
    ag[1][1] = __builtin_amdgcn_mfma_f32_16x16x32_bf16(a1, g1, ag[1][1], 0, 0, 0);
    au[0][0] = __builtin_amdgcn_mfma_f32_16x16x32_bf16(a0, u0, au[0][0], 0, 0, 0);
    au[0][1] = __builtin_amdgcn_mfma_f32_16x16x32_bf16(a0, u1, au[0][1], 0, 0, 0);
    au[1][0] = __builtin_amdgcn_mfma_f32_16x16x32_bf16(a1, u0, au[1][0], 0, 0, 0);
    au[1][1] = __builtin_amdgcn_mfma_f32_16x16x32_bf16(a1, u1, au[1][1], 0, 0, 0);
  };
  preloadA(0); stageA(0);
  preloadA(32); preloadB(64);
  BAR();
  int p = 0;
  for (int k0 = 0; k0 < HID; k0 += 64) {
    if (k0 + 32 < HID) stageA(p ^ 1);
    if (k0 + 96 < HID) preloadA(k0 + 96);
    compute(p);
    BAR(); p ^= 1;
    if (k0 + 64 < HID) stageB(p ^ 1);
    if (k0 + 128 < HID) preloadB(k0 + 128);
    compute(p);
    BAR(); p ^= 1;
  }
#pragma unroll
  for (int mt = 0; mt < 2; mt++)
#pragma unroll
    for (int nt = 0; nt < 2; nt++)
#pragma unroll
      for (int i = 0; i < 4; i++) {
        int lrow = m0 + wr + mt * 16 + lq * 4 + i;
        if (lrow < ce) {
          int gc = n0 + wc + nt * 16 + lm;
          float g = ag[mt][nt][i], u = au[mt][nt][i];
          float a = g / (1.0f + expf(-g)) * u;
          aws[((size_t)(be + lrow)) * FFD + gc] = (__bf16)a;
        }
      }
}

// down GEMM, 64x64, dbuf + 2-deep reg prefetch; weighted atomic scatter.
// grid (HID/64, MAXBLK) over the dense btab. Raw barriers (no drain).
__global__ __launch_bounds__(256) void gemm_down3(
    const __bf16* __restrict__ aws, const float* __restrict__ w_down,
    const int* __restrict__ cnt, const int* __restrict__ base,
    const int* __restrict__ list, const float* __restrict__ wt,
    const int* __restrict__ btab, const int* __restrict__ nblk,
    float* __restrict__ outp) {
  int slot = blockIdx.y;
  if (slot >= *nblk) return;
  int e = btab[2 * slot], m0 = btab[2 * slot + 1];
  int ce = cnt[e];
  int n0 = blockIdx.x * 64;
  int be = base[e];
  __shared__ __bf16 As[2][PL], Bs[2][PL];  // 20 KB
  int tid = threadIdx.x, r = tid >> 2, c8 = (tid & 3) * 8;
  int ridx = m0 + r; if (ridx >= ce) ridx = ce - 1;
  const __bf16* arow = aws + (size_t)(be + ridx) * FFD + c8;
  const float* brow = w_down + ((size_t)e * HID + n0 + r) * FFD + c8;
  int lane = tid & 63, wid = tid >> 6;
  int wr = (wid >> 1) * 32, wc = (wid & 1) * 32, lq = lane >> 4, lm = lane & 15;
  int sidx = r * LDP + c8;
  f32x4 acc[2][2] = {};
  int4 raA, raB; float4 rbA0, rbA1, rbB0, rbB1;
  auto preloadA = [&](int k0) {
    raA = *(const int4*)(arow + k0);
    rbA0 = *(const float4*)(brow + k0); rbA1 = *(const float4*)(brow + k0 + 4);
  };
  auto preloadB = [&](int k0) {
    raB = *(const int4*)(arow + k0);
    rbB0 = *(const float4*)(brow + k0); rbB1 = *(const float4*)(brow + k0 + 4);
  };
  auto stageA = [&](int p) {
    *(int4*)&As[p][sidx] = raA;
    cvt8(&Bs[p][sidx], rbA0, rbA1);
  };
  auto stageB = [&](int p) {
    *(int4*)&As[p][sidx] = raB;
    cvt8(&Bs[p][sidx], rbB0, rbB1);
  };
  auto compute = [&](int p) {
    bf16x8 a0 = *(const bf16x8*)(&As[p][(wr + lm) * LDP + lq * 8]);
    bf16x8 a1 = *(const bf16x8*)(&As[p][(wr + 16 + lm) * LDP + lq * 8]);
    bf16x8 b0 = *(const bf16x8*)(&Bs[p][(wc + lm) * LDP + lq * 8]);
    bf16x8 b1 = *(const bf16x8*)(&Bs[p][(wc + 16 + lm) * LDP + lq * 8]);
    acc[0][0] = __builtin_amdgcn_mfma_f32_16x16x32_bf16(a0, b0, acc[0][0], 0, 0, 0);
    acc[0][1] = __builtin_amdgcn_mfma_f32_16x16x32_bf16(a0, b1, acc[0][1], 0, 0, 0);
    acc[1][0] = __builtin_amdgcn_mfma_f32_16x16x32_bf16(a1, b0, acc[1][0], 0, 0, 0);
    acc[1][1] = __builtin_amdgcn_mfma_f32_16x16x32_bf16(a1, b1, acc[1][1], 0, 0, 0);
  };
  preloadA(0); stageA(0);
  preloadA(32); preloadB(64);
  BAR();
  int p = 0;
  for (int k0 = 0; k0 < FFD; k0 += 64) {
    if (k0 + 32 < FFD) stageA(p ^ 1);
    if (k0 + 96 < FFD) preloadA(k0 + 96);
    compute(p);
    BAR(); p ^= 1;
    if (k0 + 64 < FFD) stageB(p ^ 1);
    if (k0 + 128 < FFD) preloadB(k0 + 128);
    compute(p);
    BAR(); p ^= 1;
  }
#pragma unroll
  for (int mt = 0; mt < 2; mt++)
#pragma unroll
    for (int nt = 0; nt < 2; nt++)
#pragma unroll
      for (int i = 0; i < 4; i++) {
        int lrow = m0 + wr + mt * 16 + lq * 4 + i;
        if (lrow < ce) {
          int gc = n0 + wc + nt * 16 + lm;
          int tok = list[e * TOK + lrow];
          float wgt = wt[e * TOK + lrow];
          atomicAdd(&outp[(size_t)tok * HID + gc], wgt * acc[mt][nt][i]);
        }
      }
}

// ---------------- launcher ----------------

extern "C" void kernel_launch(void* const* d_in, const int* in_sizes, int n_in,
                              void* d_out, int out_size, void* d_ws, size_t ws_size,
                              hipStream_t stream) {
  const float* hidden = (const float*)d_in[0];
  const int* pos_ids = (const int*)d_in[1];
  const float* ln1_w = (const float*)d_in[2];
  const float* ln2_w = (const float*)d_in[3];
  const float* q_w = (const float*)d_in[4];
  const float* k_w = (const float*)d_in[5];
  const float* v_w = (const float*)d_in[6];
  const float* o_w = (const float*)d_in[7];
  const float* qn_w = (const float*)d_in[8];
  const float* kn_w = (const float*)d_in[9];
  const float* gate_w = (const float*)d_in[10];
  const float* w_gate = (const float*)d_in[11];
  const float* w_up = (const float*)d_in[12];
  const float* w_down = (const float*)d_in[13];
  float* outp = (float*)d_out;
  float* logits_out = outp + (size_t)TOK * HID;

  char* ws = (char*)d_ws;
  size_t off = 0;
  auto alloc = [&](size_t bytes) {
    void* p = ws + off;
    off += (bytes + 255) & ~(size_t)255;
    return p;
  };
  const size_t NWQ = (size_t)QKV_N * HID, NOW = (size_t)HID * HID;
  __bf16* wqp1 = (__bf16*)alloc(NWQ * 2); __bf16* wqp2 = (__bf16*)alloc(NWQ * 2);
  __bf16* owp1 = (__bf16*)alloc(NOW * 2); __bf16* owp2 = (__bf16*)alloc(NOW * 2);
  const size_t NH1 = (size_t)TOK * HID;
  __bf16* h1p1 = (__bf16*)alloc(NH1 * 2); __bf16* h1p2 = (__bf16*)alloc(NH1 * 2);
  float* qkvf = (float*)alloc((size_t)TOK * QKV_N * 4);
  const size_t NQ = (size_t)NB * NHEAD * SEQ * HDIM, NK = (size_t)NB * NKV * SEQ * HDIM;
  __bf16* qp1 = (__bf16*)alloc(NQ * 2); __bf16* qp2 = (__bf16*)alloc(NQ * 2);
  __bf16* kp1 = (__bf16*)alloc(NK * 2); __bf16* kp2 = (__bf16*)alloc(NK * 2);
  __bf16* vp1 = (__bf16*)alloc(NK * 2); __bf16* vp2 = (__bf16*)alloc(NK * 2);
  // score storage per hch chunk: fp32 plane (4B) + 2 bf16 softmax planes (4B).
  size_t fixed_rest = NH1 * 2 * 2 /*op*/ + NH1 * 4 * 2 /*x1,h2f*/ + NH1 * 2 /*h2b*/ +
                      NEXP * 4 * 2 + (size_t)NEXP * TOK * 8 +
                      (size_t)TOK * 2 * FFD * 2 + (1 << 20);
  size_t avail = (ws_size > off + fixed_rest) ? (ws_size - off - fixed_rest) : 0;
  int hch = (avail >= (size_t)16 * SEQ * SEQ * 8) ? 16 : 8;
  const size_t NP = (size_t)hch * SEQ * SEQ;
  float* spf = (float*)alloc(NP * 4);
  __bf16* sp1 = (__bf16*)alloc(NP * 2); __bf16* sp2 = (__bf16*)alloc(NP * 2);
  __bf16* op1 = (__bf16*)alloc(NH1 * 2); __bf16* op2 = (__bf16*)alloc(NH1 * 2);
  float* x1 = (float*)alloc(NH1 * 4);
  float* h2f = (float*)alloc(NH1 * 4);
  __bf16* h2b = (__bf16*)alloc(NH1 * 2);
  int* cnt = (int*)alloc(NEXP * 4);
  int* base = (int*)alloc((NEXP + 1) * 4);
  int* list = (int*)alloc((size_t)NEXP * TOK * 4);
  float* wt = (float*)alloc((size_t)NEXP * TOK * 4);
  int* btab = (int*)alloc((size_t)MAXBLK * 2 * 4);
  int* nblk = (int*)alloc(4);
  __bf16* aws = (__bf16*)alloc((size_t)TOK * 2 * FFD * 2);
  (void)in_sizes; (void)n_in; (void)out_size;

  // weight splits
  split2_kernel<<<1024, 256, 0, stream>>>(q_w, wqp1, wqp2, 1024 * 1024);
  split2_kernel<<<256, 256, 0, stream>>>(k_w, wqp1 + 1024 * 1024, wqp2 + 1024 * 1024,
                                         256 * 1024);
  split2_kernel<<<256, 256, 0, stream>>>(v_w, wqp1 + 1280 * 1024, wqp2 + 1280 * 1024,
                                         256 * 1024);
  split2_kernel<<<1024, 256, 0, stream>>>(o_w, owp1, owp2, 1024 * 1024);

  // attention (double-split MFMA: error ~eps^2, far below MoE bf16 floor)
  rmsnorm_split2_kernel<<<TOK, 256, 0, stream>>>(hidden, ln1_w, h1p1, h1p2);
  gemm_qkv4<<<dim3(TOK / 64, QKV_N / 64), 256, 0, stream>>>(
      h1p1, h1p2, wqp1, wqp2, qkvf);
  rope_split_kernel<<<TOK, 256, 0, stream>>>(qkvf, pos_ids, qn_w, kn_w,
                                             qp1, qp2, kp1, kp2, vp1, vp2);
  for (int b = 0; b < NB; b++)
    for (int hc = 0; hc < NHEAD / hch; hc++) {
      int h0 = hc * hch;
      gemm_scores4<<<dim3(SEQ / 64, SEQ / 64, hch), 256, 0, stream>>>(
          qp1, qp2, kp1, kp2, spf, b, h0);
      softmax2_kernel<<<hch * SEQ, 256, 0, stream>>>(spf, sp1, sp2);
      gemm_pv4<<<dim3(SEQ / 64, 1, hch), 256, 0, stream>>>(
          sp1, sp2, vp1, vp2, op1, op2, b, h0);
    }
  gemm_oproj4<<<dim3(TOK / 64, HID / 64), 256, 0, stream>>>(
      op1, op2, owp1, owp2, hidden, x1, outp);

  // MoE
  rmsnorm_dual_kernel<<<TOK, 256, 0, stream>>>(x1, ln2_w, h2f, h2b);
  zero_cnt_kernel<<<1, 64, 0, stream>>>(cnt);
  gating_kernel<<<TOK, 64, 0, stream>>>(h2f, gate_w, logits_out, cnt, list, wt);
  scan_kernel<<<1, 1, 0, stream>>>(cnt, base, btab, nblk);
  gemm_gateup3<<<dim3(FFD / 64, MAXBLK), 256, 0, stream>>>(
      h2b, w_gate, w_up, cnt, base, list, btab, nblk, aws);
  gemm_down3<<<dim3(HID / 64, MAXBLK), 256, 0, stream>>>(
      aws, w_down, cnt, base, list, wt, btab, nblk, outp);
}

// Round 7
// 533.256 us; speedup vs baseline: 1.0145x; 1.0145x over previous
//
#include <hip/hip_runtime.h>
#include <hip/hip_bf16.h>
#include <math.h>

typedef __bf16 bf16x8 __attribute__((ext_vector_type(8)));
typedef float f32x4 __attribute__((ext_vector_type(4)));

constexpr int HID = 1024;
constexpr int NHEAD = 16;
constexpr int NKV = 4;
constexpr int HDIM = 64;
constexpr int NEXP = 16;
constexpr int FFD = 1024;
constexpr int NB = 2;
constexpr int SEQ = 1024;
constexpr int TOK = NB * SEQ;
constexpr int QKV_N = NHEAD * HDIM + 2 * NKV * HDIM;  // 1536
constexpr float RMS_EPS = 1e-6f;
constexpr int LDP = 32;          // LDS row stride (bf16) — no pad; XOR swizzle instead
constexpr int PL = 64 * LDP;     // one 64-row LDS plane (4 KB)
constexpr int MAXBLK = 2 * TOK / 64 + NEXP;  // 80: max MoE m-block slots

// Conflict-free LDS addressing. Rounds 0-6: SQ_LDS_BANK_CONFLICT constant at
// 6.88M (gateup) — ~5.8 extra cyc per LDS instr; LDS pipe ≈45% of CU time and
// is the shared serializer (explains invariance to occupancy/prefetch/grid/
// barrier changes). Old LDP=40 (80B row = 20 banks, gcd(20,32)=4) collapsed
// 16 lanes onto 8 bank-groups. New: 64B rows + XOR of 16B-chunk index with
// row bits -> any 8-lane phase group covers all 32 banks bijectively
// (slots 4*(row&1) + (lq ^ ((row>>1)&3)) = permutation of 0..7), both for
// ds_read_b128 (row varies across lanes) and ds_write_b128 (2 rows x 4 cols
// per 8 threads). Same swizzle applied on write and read.
__device__ __forceinline__ int swz(int row, int e8) {
  return row * LDP + (e8 ^ (((row >> 1) & 3) << 3));
}

// x = h1 + h2 with h2 ~ eps*x (residual sub exact). Double-split: product
// error ~eps^2 ~1.5e-5 relative — 3 orders below the MoE bf16 error floor
// (absmax 0.015625 set by the single-bf16 MoE path).
__device__ __forceinline__ void split2(float x, __bf16& h1, __bf16& h2) {
  h1 = (__bf16)x;
  h2 = (__bf16)(x - (float)h1);
}

// 3-combination double-split MFMA step: a1b1 + a1b2 + a2b1, error ~eps^2.
// Planes in LDS: A1 @0, A2 @PL, B1 @2PL, B2 @3PL (plane size 4KB = swizzle-
// pattern preserving, 4096B % 128B == 0).
__device__ __forceinline__ void mfma_step3(const __bf16* sm, int wr, int wc,
                                           int lm, int lq, f32x4 (&acc)[2][2]) {
  int ao0 = swz(wr + lm, lq * 8), ao1 = ao0 + 16 * LDP;  // (row+16) keeps swz bits
  int bo0 = swz(wc + lm, lq * 8), bo1 = bo0 + 16 * LDP;
  bf16x8 a10 = *(const bf16x8*)(sm + ao0),          a11 = *(const bf16x8*)(sm + ao1);
  bf16x8 a20 = *(const bf16x8*)(sm + PL + ao0),     a21 = *(const bf16x8*)(sm + PL + ao1);
  bf16x8 b10 = *(const bf16x8*)(sm + 2 * PL + bo0), b11 = *(const bf16x8*)(sm + 2 * PL + bo1);
  bf16x8 b20 = *(const bf16x8*)(sm + 3 * PL + bo0), b21 = *(const bf16x8*)(sm + 3 * PL + bo1);
#define MF(A, B, i, j) acc[i][j] = __builtin_amdgcn_mfma_f32_16x16x32_bf16(A, B, acc[i][j], 0, 0, 0)
  MF(a10, b10, 0, 0); MF(a10, b11, 0, 1); MF(a11, b10, 1, 0); MF(a11, b11, 1, 1);
  MF(a10, b20, 0, 0); MF(a10, b21, 0, 1); MF(a11, b20, 1, 0); MF(a11, b21, 1, 1);
  MF(a20, b10, 0, 0); MF(a20, b11, 0, 1); MF(a21, b10, 1, 0); MF(a21, b11, 1, 1);
#undef MF
}

__device__ __forceinline__ void cvt8(__bf16* dst, float4 f0, float4 f1) {
  __bf16 tmp[8] __attribute__((aligned(16))) = {
      (__bf16)f0.x, (__bf16)f0.y, (__bf16)f0.z, (__bf16)f0.w,
      (__bf16)f1.x, (__bf16)f1.y, (__bf16)f1.z, (__bf16)f1.w};
  *(int4*)dst = *(const int4*)tmp;
}

// ---------------- pre/post small kernels ----------------

__global__ __launch_bounds__(256) void split2_kernel(
    const float* __restrict__ src, __bf16* __restrict__ p1,
    __bf16* __restrict__ p2, int n) {
  int i = (blockIdx.x * 256 + threadIdx.x) * 4;
  if (i >= n) return;
  float4 v = *(const float4*)(src + i);
  __bf16 t1[4] __attribute__((aligned(8))), t2[4] __attribute__((aligned(8)));
  split2(v.x, t1[0], t2[0]);
  split2(v.y, t1[1], t2[1]);
  split2(v.z, t1[2], t2[2]);
  split2(v.w, t1[3], t2[3]);
  *(int2*)(p1 + i) = *(const int2*)t1;
  *(int2*)(p2 + i) = *(const int2*)t2;
}

__global__ __launch_bounds__(256) void rmsnorm_split2_kernel(
    const float* __restrict__ x, const float* __restrict__ w,
    __bf16* __restrict__ p1, __bf16* __restrict__ p2) {
  int row = blockIdx.x;
  const float* xr = x + (size_t)row * HID;
  float4 v = ((const float4*)xr)[threadIdx.x];
  float ss = v.x * v.x + v.y * v.y + v.z * v.z + v.w * v.w;
  for (int off = 32; off; off >>= 1) ss += __shfl_xor(ss, off);
  __shared__ float red[4];
  int lane = threadIdx.x & 63, wid = threadIdx.x >> 6;
  if (lane == 0) red[wid] = ss;
  __syncthreads();
  float tot = red[0] + red[1] + red[2] + red[3];
  float scale = rsqrtf(tot / (float)HID + RMS_EPS);
  float4 wv = ((const float4*)w)[threadIdx.x];
  float o[4] = {v.x * scale * wv.x, v.y * scale * wv.y,
                v.z * scale * wv.z, v.w * scale * wv.w};
  __bf16 t1[4] __attribute__((aligned(8))), t2[4] __attribute__((aligned(8)));
#pragma unroll
  for (int i = 0; i < 4; i++) split2(o[i], t1[i], t2[i]);
  size_t idx = (size_t)row * HID + threadIdx.x * 4;
  *(int2*)(p1 + idx) = *(const int2*)t1;
  *(int2*)(p2 + idx) = *(const int2*)t2;
}

__global__ __launch_bounds__(256) void rmsnorm_dual_kernel(
    const float* __restrict__ x, const float* __restrict__ w,
    float* __restrict__ outf, __bf16* __restrict__ outb) {
  int row = blockIdx.x;
  const float* xr = x + (size_t)row * HID;
  float4 v = ((const float4*)xr)[threadIdx.x];
  float ss = v.x * v.x + v.y * v.y + v.z * v.z + v.w * v.w;
  for (int off = 32; off; off >>= 1) ss += __shfl_xor(ss, off);
  __shared__ float red[4];
  int lane = threadIdx.x & 63, wid = threadIdx.x >> 6;
  if (lane == 0) red[wid] = ss;
  __syncthreads();
  float tot = red[0] + red[1] + red[2] + red[3];
  float scale = rsqrtf(tot / (float)HID + RMS_EPS);
  float4 wv = ((const float4*)w)[threadIdx.x];
  float o[4] = {v.x * scale * wv.x, v.y * scale * wv.y,
                v.z * scale * wv.z, v.w * scale * wv.w};
  size_t idx = (size_t)row * HID + threadIdx.x * 4;
  *(float4*)(outf + idx) = *(const float4*)o;
  __bf16 tb[4] __attribute__((aligned(8)));
#pragma unroll
  for (int i = 0; i < 4; i++) tb[i] = (__bf16)o[i];
  *(int2*)(outb + idx) = *(const int2*)tb;
}

__global__ __launch_bounds__(256) void rope_split_kernel(
    const float* __restrict__ qkv, const int* __restrict__ pos_ids,
    const float* __restrict__ qn_w, const float* __restrict__ kn_w,
    __bf16* __restrict__ qp1, __bf16* __restrict__ qp2,
    __bf16* __restrict__ kp1, __bf16* __restrict__ kp2,
    __bf16* __restrict__ vp1, __bf16* __restrict__ vp2) {
  int t = blockIdx.x;
  int b = t >> 10, s = t & 1023;
  int lane = threadIdx.x & 63, w = threadIdx.x >> 6;
  float pos = (float)pos_ids[t];
  int fi = lane & 31;
  float inv = powf(10000.0f, -((float)(2 * fi)) / 64.0f);
  float cs = cosf(pos * inv), sn = sinf(pos * inv);
  for (int i = 0; i < 6; i++) {
    int hh = w + 4 * i;  // 0-15 q heads, 16-19 k heads, 20-23 v heads
    float val = qkv[(size_t)t * QKV_N + hh * 64 + lane];
    __bf16 h1, h2;
    if (hh < 20) {
      float ss = val * val;
      for (int off = 32; off; off >>= 1) ss += __shfl_xor(ss, off);
      float scale = rsqrtf(ss / 64.0f + RMS_EPS);
      float wgt = (hh < 16) ? qn_w[lane] : kn_w[lane];
      val = val * scale * wgt;
      float partner = __shfl_xor(val, 32);
      float rot = (lane < 32) ? -partner : partner;
      val = val * cs + rot * sn;
      split2(val, h1, h2);
      if (hh < 16) {
        size_t idx = (((size_t)b * NHEAD + hh) * SEQ + s) * HDIM + lane;
        qp1[idx] = h1; qp2[idx] = h2;
      } else {
        size_t idx = (((size_t)b * NKV + (hh - 16)) * SEQ + s) * HDIM + lane;
        kp1[idx] = h1; kp2[idx] = h2;
      }
    } else {
      split2(val, h1, h2);
      size_t idx = (((size_t)b * NKV + (hh - 20)) * HDIM + lane) * SEQ + s;
      vp1[idx] = h1; vp2[idx] = h2;
    }
  }
}

// scores land as a single fp32 plane; softmax emits 2 bf16 planes for PV.
__global__ __launch_bounds__(256) void softmax2_kernel(
    const float* __restrict__ sf,
    __bf16* __restrict__ p1, __bf16* __restrict__ p2) {
  size_t roff = (size_t)blockIdx.x * SEQ;
  int tid = threadIdx.x;
  float4 v4 = *(const float4*)(sf + roff + tid * 4);
  float v[4] = {v4.x, v4.y, v4.z, v4.w};
  float mx = fmaxf(fmaxf(v[0], v[1]), fmaxf(v[2], v[3]));
  for (int off = 32; off; off >>= 1) mx = fmaxf(mx, __shfl_xor(mx, off));
  __shared__ float red[4], red2[4];
  int lane = tid & 63, wid = tid >> 6;
  if (lane == 0) red[wid] = mx;
  __syncthreads();
  mx = fmaxf(fmaxf(red[0], red[1]), fmaxf(red[2], red[3]));
  float e[4], sum = 0.f;
#pragma unroll
  for (int i = 0; i < 4; i++) { e[i] = expf(v[i] - mx); sum += e[i]; }
  for (int off = 32; off; off >>= 1) sum += __shfl_xor(sum, off);
  if (lane == 0) red2[wid] = sum;
  __syncthreads();
  sum = red2[0] + red2[1] + red2[2] + red2[3];
  float invs = 1.0f / sum;
  __bf16 t1[4] __attribute__((aligned(8))), t2[4] __attribute__((aligned(8)));
#pragma unroll
  for (int i = 0; i < 4; i++) split2(e[i] * invs, t1[i], t2[i]);
  *(int2*)(p1 + roff + tid * 4) = *(const int2*)t1;
  *(int2*)(p2 + roff + tid * 4) = *(const int2*)t2;
}

// ------------- double-split GEMMs (64x64 tile, BK=32) -------------
// 2-deep register prefetch (named sets A/B, unroll-2 — rule #20) + LDS dbuf,
// conflict-free XOR-swizzled LDS (LDP=32), 1 barrier/step.

__global__ __launch_bounds__(256) void gemm_qkv4(
    const __bf16* __restrict__ a1, const __bf16* __restrict__ a2,
    const __bf16* __restrict__ b1, const __bf16* __restrict__ b2,
    float* __restrict__ qkv) {
  int m0 = blockIdx.x * 64, n0 = blockIdx.y * 64;
  __shared__ __bf16 sm[2][4 * PL];  // 32 KB
  int tid = threadIdx.x, r = tid >> 2, c8 = (tid & 3) * 8;
  size_t aoff = (size_t)(m0 + r) * HID + c8, boff = (size_t)(n0 + r) * HID + c8;
  f32x4 acc[2][2] = {};
  int lane = tid & 63, wid = tid >> 6;
  int wr = (wid >> 1) * 32, wc = (wid & 1) * 32, lq = lane >> 4, lm = lane & 15;
  int sidx = swz(r, c8);
  int4 rA1, rA2, rA3, rA4, rB1, rB2, rB3, rB4;
  auto preloadA = [&](int k0) {
    rA1 = *(const int4*)(a1 + aoff + k0); rA2 = *(const int4*)(a2 + aoff + k0);
    rA3 = *(const int4*)(b1 + boff + k0); rA4 = *(const int4*)(b2 + boff + k0);
  };
  auto preloadB = [&](int k0) {
    rB1 = *(const int4*)(a1 + aoff + k0); rB2 = *(const int4*)(a2 + aoff + k0);
    rB3 = *(const int4*)(b1 + boff + k0); rB4 = *(const int4*)(b2 + boff + k0);
  };
  auto stageA = [&](int p) {
    *(int4*)&sm[p][0 * PL + sidx] = rA1; *(int4*)&sm[p][1 * PL + sidx] = rA2;
    *(int4*)&sm[p][2 * PL + sidx] = rA3; *(int4*)&sm[p][3 * PL + sidx] = rA4;
  };
  auto stageB = [&](int p) {
    *(int4*)&sm[p][0 * PL + sidx] = rB1; *(int4*)&sm[p][1 * PL + sidx] = rB2;
    *(int4*)&sm[p][2 * PL + sidx] = rB3; *(int4*)&sm[p][3 * PL + sidx] = rB4;
  };
  preloadA(0); stageA(0);
  preloadA(32); preloadB(64);
  __syncthreads();
  int p = 0;
  for (int k0 = 0; k0 < HID; k0 += 64) {
    if (k0 + 32 < HID) stageA(p ^ 1);
    if (k0 + 96 < HID) preloadA(k0 + 96);
    mfma_step3(sm[p], wr, wc, lm, lq, acc);
    __syncthreads(); p ^= 1;
    if (k0 + 64 < HID) stageB(p ^ 1);
    if (k0 + 128 < HID) preloadB(k0 + 128);
    mfma_step3(sm[p], wr, wc, lm, lq, acc);
    __syncthreads(); p ^= 1;
  }
#pragma unroll
  for (int mt = 0; mt < 2; mt++)
#pragma unroll
    for (int nt = 0; nt < 2; nt++)
#pragma unroll
      for (int i = 0; i < 4; i++) {
        int gm = m0 + wr + mt * 16 + lq * 4 + i;
        int gc = n0 + wc + nt * 16 + lm;
        qkv[(size_t)gm * QKV_N + gc] = acc[mt][nt][i];
      }
}

__global__ __launch_bounds__(256) void gemm_scores4(
    const __bf16* __restrict__ qp1, const __bf16* __restrict__ qp2,
    const __bf16* __restrict__ kp1, const __bf16* __restrict__ kp2,
    float* __restrict__ sf, int b, int h0) {
  int hz = blockIdx.z, h = h0 + hz;
  int m0 = blockIdx.x * 64, n0 = blockIdx.y * 64;
  size_t qbase = ((size_t)(b * NHEAD + h)) * SEQ * HDIM;
  size_t kbase = ((size_t)(b * NKV + (h >> 2))) * SEQ * HDIM;
  __shared__ __bf16 sm[4 * PL];  // 16 KB
  int tid = threadIdx.x, r = tid >> 2, c8 = (tid & 3) * 8;
  size_t aoff = qbase + (size_t)(m0 + r) * HDIM + c8;
  size_t boff = kbase + (size_t)(n0 + r) * HDIM + c8;
  f32x4 acc[2][2] = {};
  int lane = tid & 63, wid = tid >> 6;
  int wr = (wid >> 1) * 32, wc = (wid & 1) * 32, lq = lane >> 4, lm = lane & 15;
  int sidx = swz(r, c8);
  int4 ra1, ra2, rb1, rb2;
  auto preload = [&](int k0) {
    ra1 = *(const int4*)(qp1 + aoff + k0);
    ra2 = *(const int4*)(qp2 + aoff + k0);
    rb1 = *(const int4*)(kp1 + boff + k0);
    rb2 = *(const int4*)(kp2 + boff + k0);
  };
  auto stage = [&]() {
    *(int4*)&sm[0 * PL + sidx] = ra1;
    *(int4*)&sm[1 * PL + sidx] = ra2;
    *(int4*)&sm[2 * PL + sidx] = rb1;
    *(int4*)&sm[3 * PL + sidx] = rb2;
  };
  preload(0); stage();
  for (int k0 = 0; k0 < HDIM; k0 += 32) {
    __syncthreads();
    if (k0 + 32 < HDIM) preload(k0 + 32);
    mfma_step3(sm, wr, wc, lm, lq, acc);
    __syncthreads();
    if (k0 + 32 < HDIM) stage();
  }
#pragma unroll
  for (int mt = 0; mt < 2; mt++)
#pragma unroll
    for (int nt = 0; nt < 2; nt++)
#pragma unroll
      for (int i = 0; i < 4; i++) {
        int gm = m0 + wr + mt * 16 + lq * 4 + i;
        int gc = n0 + wc + nt * 16 + lm;
        size_t idx = ((size_t)hz * SEQ + gm) * SEQ + gc;
        sf[idx] = acc[mt][nt][i] * 0.125f;
      }
}

__global__ __launch_bounds__(256) void gemm_pv4(
    const __bf16* __restrict__ s1, const __bf16* __restrict__ s2,
    const __bf16* __restrict__ vp1, const __bf16* __restrict__ vp2,
    __bf16* __restrict__ o1, __bf16* __restrict__ o2,
    int b, int h0) {
  int hz = blockIdx.z, h = h0 + hz;
  int m0 = blockIdx.x * 64;
  size_t pbase = (size_t)hz * SEQ * SEQ;
  size_t vbase = ((size_t)(b * NKV + (h >> 2))) * HDIM * SEQ;
  __shared__ __bf16 sm[2][4 * PL];  // 32 KB
  int tid = threadIdx.x, r = tid >> 2, c8 = (tid & 3) * 8;
  size_t aoff = pbase + (size_t)(m0 + r) * SEQ + c8;
  size_t boff = vbase + (size_t)r * SEQ + c8;
  f32x4 acc[2][2] = {};
  int lane = tid & 63, wid = tid >> 6;
  int wr = (wid >> 1) * 32, wc = (wid & 1) * 32, lq = lane >> 4, lm = lane & 15;
  int sidx = swz(r, c8);
  int4 rA1, rA2, rA3, rA4, rB1, rB2, rB3, rB4;
  auto preloadA = [&](int k0) {
    rA1 = *(const int4*)(s1 + aoff + k0);  rA2 = *(const int4*)(s2 + aoff + k0);
    rA3 = *(const int4*)(vp1 + boff + k0); rA4 = *(const int4*)(vp2 + boff + k0);
  };
  auto preloadB = [&](int k0) {
    rB1 = *(const int4*)(s1 + aoff + k0);  rB2 = *(const int4*)(s2 + aoff + k0);
    rB3 = *(const int4*)(vp1 + boff + k0); rB4 = *(const int4*)(vp2 + boff + k0);
  };
  auto stageA = [&](int p) {
    *(int4*)&sm[p][0 * PL + sidx] = rA1; *(int4*)&sm[p][1 * PL + sidx] = rA2;
    *(int4*)&sm[p][2 * PL + sidx] = rA3; *(int4*)&sm[p][3 * PL + sidx] = rA4;
  };
  auto stageB = [&](int p) {
    *(int4*)&sm[p][0 * PL + sidx] = rB1; *(int4*)&sm[p][1 * PL + sidx] = rB2;
    *(int4*)&sm[p][2 * PL + sidx] = rB3; *(int4*)&sm[p][3 * PL + sidx] = rB4;
  };
  preloadA(0); stageA(0);
  preloadA(32); preloadB(64);
  __syncthreads();
  int p = 0;
  for (int k0 = 0; k0 < SEQ; k0 += 64) {
    if (k0 + 32 < SEQ) stageA(p ^ 1);
    if (k0 + 96 < SEQ) preloadA(k0 + 96);
    mfma_step3(sm[p], wr, wc, lm, lq, acc);
    __syncthreads(); p ^= 1;
    if (k0 + 64 < SEQ) stageB(p ^ 1);
    if (k0 + 128 < SEQ) preloadB(k0 + 128);
    mfma_step3(sm[p], wr, wc, lm, lq, acc);
    __syncthreads(); p ^= 1;
  }
#pragma unroll
  for (int mt = 0; mt < 2; mt++)
#pragma unroll
    for (int nt = 0; nt < 2; nt++)
#pragma unroll
      for (int i = 0; i < 4; i++) {
        int gm = m0 + wr + mt * 16 + lq * 4 + i;
        int gc = wc + nt * 16 + lm;
        size_t idx = ((size_t)(b * SEQ + gm)) * HID + h * 64 + gc;
        __bf16 h1_, h2_;
        split2(acc[mt][nt][i], h1_, h2_);
        o1[idx] = h1_; o2[idx] = h2_;
      }
}

__global__ __launch_bounds__(256) void gemm_oproj4(
    const __bf16* __restrict__ a1, const __bf16* __restrict__ a2,
    const __bf16* __restrict__ b1, const __bf16* __restrict__ b2,
    const float* __restrict__ hidden, float* __restrict__ x1, float* __restrict__ outp) {
  int m0 = blockIdx.x * 64, n0 = blockIdx.y * 64;
  __shared__ __bf16 sm[2][4 * PL];  // 32 KB
  int tid = threadIdx.x, r = tid >> 2, c8 = (tid & 3) * 8;
  size_t aoff = (size_t)(m0 + r) * HID + c8, boff = (size_t)(n0 + r) * HID + c8;
  f32x4 acc[2][2] = {};
  int lane = tid & 63, wid = tid >> 6;
  int wr = (wid >> 1) * 32, wc = (wid & 1) * 32, lq = lane >> 4, lm = lane & 15;
  int sidx = swz(r, c8);
  int4 rA1, rA2, rA3, rA4, rB1, rB2, rB3, rB4;
  auto preloadA = [&](int k0) {
    rA1 = *(const int4*)(a1 + aoff + k0); rA2 = *(const int4*)(a2 + aoff + k0);
    rA3 = *(const int4*)(b1 + boff + k0); rA4 = *(const int4*)(b2 + boff + k0);
  };
  auto preloadB = [&](int k0) {
    rB1 = *(const int4*)(a1 + aoff + k0); rB2 = *(const int4*)(a2 + aoff + k0);
    rB3 = *(const int4*)(b1 + boff + k0); rB4 = *(const int4*)(b2 + boff + k0);
  };
  auto stageA = [&](int p) {
    *(int4*)&sm[p][0 * PL + sidx] = rA1; *(int4*)&sm[p][1 * PL + sidx] = rA2;
    *(int4*)&sm[p][2 * PL + sidx] = rA3; *(int4*)&sm[p][3 * PL + sidx] = rA4;
  };
  auto stageB = [&](int p) {
    *(int4*)&sm[p][0 * PL + sidx] = rB1; *(int4*)&sm[p][1 * PL + sidx] = rB2;
    *(int4*)&sm[p][2 * PL + sidx] = rB3; *(int4*)&sm[p][3 * PL + sidx] = rB4;
  };
  preloadA(0); stageA(0);
  preloadA(32); preloadB(64);
  __syncthreads();
  int p = 0;
  for (int k0 = 0; k0 < HID; k0 += 64) {
    if (k0 + 32 < HID) stageA(p ^ 1);
    if (k0 + 96 < HID) preloadA(k0 + 96);
    mfma_step3(sm[p], wr, wc, lm, lq, acc);
    __syncthreads(); p ^= 1;
    if (k0 + 64 < HID) stageB(p ^ 1);
    if (k0 + 128 < HID) preloadB(k0 + 128);
    mfma_step3(sm[p], wr, wc, lm, lq, acc);
    __syncthreads(); p ^= 1;
  }
#pragma unroll
  for (int mt = 0; mt < 2; mt++)
#pragma unroll
    for (int nt = 0; nt < 2; nt++)
#pragma unroll
      for (int i = 0; i < 4; i++) {
        int gm = m0 + wr + mt * 16 + lq * 4 + i;
        int gc = n0 + wc + nt * 16 + lm;
        size_t idx = (size_t)gm * HID + gc;
        float val = hidden[idx] + acc[mt][nt][i];
        x1[idx] = val;
        outp[idx] = val;
      }
}

// ---------------- MoE ----------------

__global__ void zero_cnt_kernel(int* cnt) {
  if (threadIdx.x < NEXP) cnt[threadIdx.x] = 0;
}

__global__ __launch_bounds__(64) void gating_kernel(
    const float* __restrict__ h2f, const float* __restrict__ gw,
    float* __restrict__ logits_out, int* __restrict__ cnt,
    int* __restrict__ list, float* __restrict__ wt) {
  int t = blockIdx.x;
  int lane = threadIdx.x;
  const float* xr = h2f + (size_t)t * HID;
  float part[NEXP] = {};
  for (int k = lane; k < HID; k += 64) {
    float xv = xr[k];
#pragma unroll
    for (int e = 0; e < NEXP; e++) part[e] += xv * gw[e * HID + k];
  }
#pragma unroll
  for (int e = 0; e < NEXP; e++)
    for (int off = 32; off; off >>= 1) part[e] += __shfl_xor(part[e], off);
  if (lane < NEXP) logits_out[(size_t)t * NEXP + lane] = part[lane];
  float mx = part[0];
#pragma unroll
  for (int e = 1; e < NEXP; e++) mx = fmaxf(mx, part[e]);
  float pe[NEXP];
#pragma unroll
  for (int e = 0; e < NEXP; e++) pe[e] = expf(part[e] - mx);
  int e0 = 0; float p0 = pe[0];
#pragma unroll
  for (int e = 1; e < NEXP; e++) if (pe[e] > p0) { p0 = pe[e]; e0 = e; }
  int e1 = -1; float p1 = -1.f;
#pragma unroll
  for (int e = 0; e < NEXP; e++) if (e != e0 && pe[e] > p1) { p1 = pe[e]; e1 = e; }
  float wsum = p0 + p1;
  if (lane == 0) {
    int pos0 = atomicAdd(&cnt[e0], 1);
    list[e0 * TOK + pos0] = t;
    wt[e0 * TOK + pos0] = p0 / wsum;
    int pos1 = atomicAdd(&cnt[e1], 1);
    list[e1 * TOK + pos1] = t;
    wt[e1 * TOK + pos1] = p1 / wsum;
  }
}

// scan + dense block table (round-5: keeps all-CU coverage; kept).
__global__ void scan_kernel(const int* __restrict__ cnt, int* __restrict__ base,
                            int* __restrict__ btab, int* __restrict__ nblk) {
  if (threadIdx.x == 0 && blockIdx.x == 0) {
    int acc = 0, nb = 0;
    for (int e = 0; e < NEXP; e++) {
      base[e] = acc; acc += cnt[e];
      for (int m0 = 0; m0 < cnt[e]; m0 += 64) {
        btab[2 * nb] = e; btab[2 * nb + 1] = m0; nb++;
      }
    }
    base[NEXP] = acc;
    *nblk = nb;
  }
}

// fused gate+up, 64x64 tile, BK=32, LDS dbuf + 2-deep reg prefetch,
// conflict-free swizzled LDS, 1 barrier/iter. grid (FFD/64, MAXBLK) over btab.
__global__ __launch_bounds__(256) void gemm_gateup3(
    const __bf16* __restrict__ h2, const float* __restrict__ w_gate,
    const float* __restrict__ w_up, const int* __restrict__ cnt,
    const int* __restrict__ base, const int* __restrict__ list,
    const int* __restrict__ btab, const int* __restrict__ nblk,
    __bf16* __restrict__ aws) {
  int slot = blockIdx.y;
  if (slot >= *nblk) return;
  int e = btab[2 * slot], m0 = btab[2 * slot + 1];
  int ce = cnt[e];
  int n0 = blockIdx.x * 64;
  int be = base[e];
  __shared__ __bf16 As[2][PL], Bg[2][PL], Bu[2][PL];  // 24 KB
  int tid = threadIdx.x, r = tid >> 2, c8 = (tid & 3) * 8;
  int ridx = m0 + r; if (ridx >= ce) ridx = ce - 1;
  const __bf16* arow = h2 + (size_t)list[e * TOK + ridx] * HID + c8;
  const float* bgrow = w_gate + ((size_t)e * FFD + n0 + r) * HID + c8;
  const float* burow = w_up + ((size_t)e * FFD + n0 + r) * HID + c8;
  int lane = tid & 63, wid = tid >> 6;
  int wr = (wid >> 1) * 32, wc = (wid & 1) * 32, lq = lane >> 4, lm = lane & 15;
  int sidx = swz(r, c8);
  f32x4 ag[2][2] = {}, au[2][2] = {};
  int4 raA, raB; float4 rgA0, rgA1, ruA0, ruA1, rgB0, rgB1, ruB0, ruB1;
  auto preloadA = [&](int k0) {
    raA = *(const int4*)(arow + k0);
    rgA0 = *(const float4*)(bgrow + k0); rgA1 = *(const float4*)(bgrow + k0 + 4);
    ruA0 = *(const float4*)(burow + k0); ruA1 = *(const float4*)(burow + k0 + 4);
  };
  auto preloadB = [&](int k0) {
    raB = *(const int4*)(arow + k0);
    rgB0 = *(const float4*)(bgrow + k0); rgB1 = *(const float4*)(bgrow + k0 + 4);
    ruB0 = *(const float4*)(burow + k0); ruB1 = *(const float4*)(burow + k0 + 4);
  };
  auto stageA = [&](int p) {
    *(int4*)&As[p][sidx] = raA;
    cvt8(&Bg[p][sidx], rgA0, rgA1);
    cvt8(&Bu[p][sidx], ruA0, ruA1);
  };
  auto stageB = [&](int p) {
    *(int4*)&As[p][sidx] = raB;
    cvt8(&Bg[p][sidx], rgB0, rgB1);
    cvt8(&Bu[p][sidx], ruB0, ruB1);
  };
  auto compute = [&](int p) {
    int ao0 = swz(wr + lm, lq * 8), ao1 = ao0 + 16 * LDP;
    int bo0 = swz(wc + lm, lq * 8), bo1 = bo0 + 16 * LDP;
    bf16x8 a0 = *(const bf16x8*)(&As[p][ao0]);
    bf16x8 a1 = *(const bf16x8*)(&As[p][ao1]);
    bf16x8 g0 = *(const bf16x8*)(&Bg[p][bo0]);
    bf16x8 g1 = *(const bf16x8*)(&Bg[p][bo1]);
    bf16x8 u0 = *(const bf16x8*)(&Bu[p][bo0]);
    bf16x8 u1 = *(const bf16x8*)(&Bu[p][bo1]);
    ag[0][0] = __builtin_amdgcn_mfma_f32_16x16x32_bf16(a0, g0, ag[0][0], 0, 0, 0);
    ag[0][1] = __builtin_amdgcn_mfma_f32_16x16x32_bf16(a0, g1, ag[0][1], 0, 0, 0);
    ag[1][0] = __builtin_amdgcn_mfma_f32_16x16x32_bf16(a1, g0, ag[1][0], 0, 0, 0);
    ag[1][1] = __builtin_amdgcn_mfma_f32_16x16x32_bf16(a1, g1, ag[1][1], 0, 0, 0);
    au[0][0] = __builtin_amdgcn_mfma_f32_16x16x32_bf16(a0, u0, au[0][0], 0, 0, 0);
    au[0][1] = __builtin_amdgcn_mfma_f32_16x16x32_bf16(a0, u1, au[0][1], 0, 0, 0);
    au[1][0] = __builtin_amdgcn_mfma_f32_16x16x32_bf16(a1, u0, au[1][0], 0, 0, 0);
    au[1][1] = __builtin_amdgcn_mfma_f32_16x16x32_bf16(a1, u1, au[1][1], 0, 0, 0);
  };
  preloadA(0); stageA(0);
  preloadA(32); preloadB(64);
  __syncthreads();
  int p = 0;
  for (int k0 = 0; k0 < HID; k0 += 64) {
    if (k0 + 32 < HID) stageA(p ^ 1);
    if (k0 + 96 < HID) preloadA(k0 + 96);
    compute(p);
    __syncthreads(); p ^= 1;
    if (k0 + 64 < HID) stageB(p ^ 1);
    if (k0 + 128 < HID) preloadB(k0 + 128);
    compute(p);
    __syncthreads(); p ^= 1;
  }
#pragma unroll
  for (int mt = 0; mt < 2; mt++)
#pragma unroll
    for (int nt = 0; nt < 2; nt++)
#pragma unroll
      for (int i = 0; i < 4; i++) {
        int lrow = m0 + wr + mt * 16 + lq * 4 + i;
        if (lrow < ce) {
          int gc = n0 + wc + nt * 16 + lm;
          float g = ag[mt][nt][i], u = au[mt][nt][i];
          float a = g / (1.0f + expf(-g)) * u;
          aws[((size_t)(be + lrow)) * FFD + gc] = (__bf16)a;
        }
      }
}

// down GEMM, 64x64, dbuf + 2-deep reg prefetch, swizzled LDS; atomic scatter.
// grid (HID/64, MAXBLK) over the dense btab.
__global__ __launch_bounds__(256) void gemm_down3(
    const __bf16* __restrict__ aws, const float* __restrict__ w_down,
    const int* __restrict__ cnt, const int* __restrict__ base,
    const int* __restrict__ list, const float* __restrict__ wt,
    const int* __restrict__ btab, const int* __restrict__ nblk,
    float* __restrict__ outp) {
  int slot = blockIdx.y;
  if (slot >= *nblk) return;
  int e = btab[2 * slot], m0 = btab[2 * slot + 1];
  int ce = cnt[e];
  int n0 = blockIdx.x * 64;
  int be = base[e];
  __shared__ __bf16 As[2][PL], Bs[2][PL];  // 16 KB
  int tid = threadIdx.x, r = tid >> 2, c8 = (tid & 3) * 8;
  int ridx = m0 + r; if (ridx >= ce) ridx = ce - 1;
  const __bf16* arow = aws + (size_t)(be + ridx) * FFD + c8;
  const float* brow = w_down + ((size_t)e * HID + n0 + r) * FFD + c8;
  int lane = tid & 63, wid = tid >> 6;
  int wr = (wid >> 1) * 32, wc = (wid & 1) * 32, lq = lane >> 4, lm = lane & 15;
  int sidx = swz(r, c8);
  f32x4 acc[2][2] = {};
  int4 raA, raB; float4 rbA0, rbA1, rbB0, rbB1;
  auto preloadA = [&](int k0) {
    raA = *(const int4*)(arow + k0);
    rbA0 = *(const float4*)(brow + k0); rbA1 = *(const float4*)(brow + k0 + 4);
  };
  auto preloadB = [&](int k0) {
    raB = *(const int4*)(arow + k0);
    rbB0 = *(const float4*)(brow + k0); rbB1 = *(const float4*)(brow + k0 + 4);
  };
  auto stageA = [&](int p) {
    *(int4*)&As[p][sidx] = raA;
    cvt8(&Bs[p][sidx], rbA0, rbA1);
  };
  auto stageB = [&](int p) {
    *(int4*)&As[p][sidx] = raB;
    cvt8(&Bs[p][sidx], rbB0, rbB1);
  };
  auto compute = [&](int p) {
    int ao0 = swz(wr + lm, lq * 8), ao1 = ao0 + 16 * LDP;
    int bo0 = swz(wc + lm, lq * 8), bo1 = bo0 + 16 * LDP;
    bf16x8 a0 = *(const bf16x8*)(&As[p][ao0]);
    bf16x8 a1 = *(const bf16x8*)(&As[p][ao1]);
    bf16x8 b0 = *(const bf16x8*)(&Bs[p][bo0]);
    bf16x8 b1 = *(const bf16x8*)(&Bs[p][bo1]);
    acc[0][0] = __builtin_amdgcn_mfma_f32_16x16x32_bf16(a0, b0, acc[0][0], 0, 0, 0);
    acc[0][1] = __builtin_amdgcn_mfma_f32_16x16x32_bf16(a0, b1, acc[0][1], 0, 0, 0);
    acc[1][0] = __builtin_amdgcn_mfma_f32_16x16x32_bf16(a1, b0, acc[1][0], 0, 0, 0);
    acc[1][1] = __builtin_amdgcn_mfma_f32_16x16x32_bf16(a1, b1, acc[1][1], 0, 0, 0);
  };
  preloadA(0); stageA(0);
  preloadA(32); preloadB(64);
  __syncthreads();
  int p = 0;
  for (int k0 = 0; k0 < FFD; k0 += 64) {
    if (k0 + 32 < FFD) stageA(p ^ 1);
    if (k0 + 96 < FFD) preloadA(k0 + 96);
    compute(p);
    __syncthreads(); p ^= 1;
    if (k0 + 64 < FFD) stageB(p ^ 1);
    if (k0 + 128 < FFD) preloadB(k0 + 128);
    compute(p);
    __syncthreads(); p ^= 1;
  }
#pragma unroll
  for (int mt = 0; mt < 2; mt++)
#pragma unroll
    for (int nt = 0; nt < 2; nt++)
#pragma unroll
      for (int i = 0; i < 4; i++) {
        int lrow = m0 + wr + mt * 16 + lq * 4 + i;
        if (lrow < ce) {
          int gc = n0 + wc + nt * 16 + lm;
          int tok = list[e * TOK + lrow];
          float wgt = wt[e * TOK + lrow];
          atomicAdd(&outp[(size_t)tok * HID + gc], wgt * acc[mt][nt][i]);
        }
      }
}

// ---------------- launcher ----------------

extern "C" void kernel_launch(void* const* d_in, const int* in_sizes, int n_in,
                              void* d_out, int out_size, void* d_ws, size_t ws_size,
                              hipStream_t stream) {
  const float* hidden = (const float*)d_in[0];
  const int* pos_ids = (const int*)d_in[1];
  const float* ln1_w = (const float*)d_in[2];
  const float* ln2_w = (const float*)d_in[3];
  const float* q_w = (const float*)d_in[4];
  const float* k_w = (const float*)d_in[5];
  const float* v_w = (const float*)d_in[6];
  const float* o_w = (const float*)d_in[7];
  const float* qn_w = (const float*)d_in[8];
  const float* kn_w = (const float*)d_in[9];
  const float* gate_w = (const float*)d_in[10];
  const float* w_gate = (const float*)d_in[11];
  const float* w_up = (const float*)d_in[12];
  const float* w_down = (const float*)d_in[13];
  float* outp = (float*)d_out;
  float* logits_out = outp + (size_t)TOK * HID;

  char* ws = (char*)d_ws;
  size_t off = 0;
  auto alloc = [&](size_t bytes) {
    void* p = ws + off;
    off += (bytes + 255) & ~(size_t)255;
    return p;
  };
  const size_t NWQ = (size_t)QKV_N * HID, NOW = (size_t)HID * HID;
  __bf16* wqp1 = (__bf16*)alloc(NWQ * 2); __bf16* wqp2 = (__bf16*)alloc(NWQ * 2);
  __bf16* owp1 = (__bf16*)alloc(NOW * 2); __bf16* owp2 = (__bf16*)alloc(NOW * 2);
  const size_t NH1 = (size_t)TOK * HID;
  __bf16* h1p1 = (__bf16*)alloc(NH1 * 2); __bf16* h1p2 = (__bf16*)alloc(NH1 * 2);
  float* qkvf = (float*)alloc((size_t)TOK * QKV_N * 4);
  const size_t NQ = (size_t)NB * NHEAD * SEQ * HDIM, NK = (size_t)NB * NKV * SEQ * HDIM;
  __bf16* qp1 = (__bf16*)alloc(NQ * 2); __bf16* qp2 = (__bf16*)alloc(NQ * 2);
  __bf16* kp1 = (__bf16*)alloc(NK * 2); __bf16* kp2 = (__bf16*)alloc(NK * 2);
  __bf16* vp1 = (__bf16*)alloc(NK * 2); __bf16* vp2 = (__bf16*)alloc(NK * 2);
  // score storage per hch chunk: fp32 plane (4B) + 2 bf16 softmax planes (4B).
  size_t fixed_rest = NH1 * 2 * 2 /*op*/ + NH1 * 4 * 2 /*x1,h2f*/ + NH1 * 2 /*h2b*/ +
                      NEXP * 4 * 2 + (size_t)NEXP * TOK * 8 +
                      (size_t)TOK * 2 * FFD * 2 + (1 << 20);
  size_t avail = (ws_size > off + fixed_rest) ? (ws_size - off - fixed_rest) : 0;
  int hch = (avail >= (size_t)16 * SEQ * SEQ * 8) ? 16 : 8;
  const size_t NP = (size_t)hch * SEQ * SEQ;
  float* spf = (float*)alloc(NP * 4);
  __bf16* sp1 = (__bf16*)alloc(NP * 2); __bf16* sp2 = (__bf16*)alloc(NP * 2);
  __bf16* op1 = (__bf16*)alloc(NH1 * 2); __bf16* op2 = (__bf16*)alloc(NH1 * 2);
  float* x1 = (float*)alloc(NH1 * 4);
  float* h2f = (float*)alloc(NH1 * 4);
  __bf16* h2b = (__bf16*)alloc(NH1 * 2);
  int* cnt = (int*)alloc(NEXP * 4);
  int* base = (int*)alloc((NEXP + 1) * 4);
  int* list = (int*)alloc((size_t)NEXP * TOK * 4);
  float* wt = (float*)alloc((size_t)NEXP * TOK * 4);
  int* btab = (int*)alloc((size_t)MAXBLK * 2 * 4);
  int* nblk = (int*)alloc(4);
  __bf16* aws = (__bf16*)alloc((size_t)TOK * 2 * FFD * 2);
  (void)in_sizes; (void)n_in; (void)out_size;

  // weight splits
  split2_kernel<<<1024, 256, 0, stream>>>(q_w, wqp1, wqp2, 1024 * 1024);
  split2_kernel<<<256, 256, 0, stream>>>(k_w, wqp1 + 1024 * 1024, wqp2 + 1024 * 1024,
                                         256 * 1024);
  split2_kernel<<<256, 256, 0, stream>>>(v_w, wqp1 + 1280 * 1024, wqp2 + 1280 * 1024,
                                         256 * 1024);
  split2_kernel<<<1024, 256, 0, stream>>>(o_w, owp1, owp2, 1024 * 1024);

  // attention (double-split MFMA: error ~eps^2, far below MoE bf16 floor)
  rmsnorm_split2_kernel<<<TOK, 256, 0, stream>>>(hidden, ln1_w, h1p1, h1p2);
  gemm_qkv4<<<dim3(TOK / 64, QKV_N / 64), 256, 0, stream>>>(
      h1p1, h1p2, wqp1, wqp2, qkvf);
  rope_split_kernel<<<TOK, 256, 0, stream>>>(qkvf, pos_ids, qn_w, kn_w,
                                             qp1, qp2, kp1, kp2, vp1, vp2);
  for (int b = 0; b < NB; b++)
    for (int hc = 0; hc < NHEAD / hch; hc++) {
      int h0 = hc * hch;
      gemm_scores4<<<dim3(SEQ / 64, SEQ / 64, hch), 256, 0, stream>>>(
          qp1, qp2, kp1, kp2, spf, b, h0);
      softmax2_kernel<<<hch * SEQ, 256, 0, stream>>>(spf, sp1, sp2);
      gemm_pv4<<<dim3(SEQ / 64, 1, hch), 256, 0, stream>>>(
          sp1, sp2, vp1, vp2, op1, op2, b, h0);
    }
  gemm_oproj4<<<dim3(TOK / 64, HID / 64), 256, 0, stream>>>(
      op1, op2, owp1, owp2, hidden, x1, outp);

  // MoE
  rmsnorm_dual_kernel<<<TOK, 256, 0, stream>>>(x1, ln2_w, h2f, h2b);
  zero_cnt_kernel<<<1, 64, 0, stream>>>(cnt);
  gating_kernel<<<TOK, 64, 0, stream>>>(h2f, gate_w, logits_out, cnt, list, wt);
  scan_kernel<<<1, 1, 0, stream>>>(cnt, base, btab, nblk);
  gemm_gateup3<<<dim3(FFD / 64, MAXBLK), 256, 0, stream>>>(
      h2b, w_gate, w_up, cnt, base, list, btab, nblk, aws);
  gemm_down3<<<dim3(HID / 64, MAXBLK), 256, 0, stream>>>(
      aws, w_down, cnt, base, list, wt, btab, nblk, outp);
}

// Round 8
// 531.919 us; speedup vs baseline: 1.0171x; 1.0025x over previous
//
#include <hip/hip_runtime.h>
#include <hip/hip_bf16.h>
#include <math.h>

typedef __bf16 bf16x8 __attribute__((ext_vector_type(8)));
typedef float f32x4 __attribute__((ext_vector_type(4)));

constexpr int HID = 1024;
constexpr int NHEAD = 16;
constexpr int NKV = 4;
constexpr int HDIM = 64;
constexpr int NEXP = 16;
constexpr int FFD = 1024;
constexpr int NB = 2;
constexpr int SEQ = 1024;
constexpr int TOK = NB * SEQ;
constexpr int QKV_N = NHEAD * HDIM + 2 * NKV * HDIM;  // 1536
constexpr float RMS_EPS = 1e-6f;
constexpr int LDP = 32;          // LDS row stride (bf16): 64B rows, XOR swizzle
constexpr int PL = 64 * LDP;     // one 64-row LDS plane (4 KB)
constexpr int MAXBLK = 2 * TOK / 128 + NEXP;  // 48: max 128-row MoE m-block slots

// Round-7 result: conflicts 6.88M -> 0 (swizzle exact) but gateup only -7%.
// Recount: LDS pipe executes ~9800 b128 instrs/CU x ~12cy = ~70% of runtime
// even conflict-free — BASE LDS INSTRUCTION COUNT is the CU-shared serializer
// (explains all rounds-0..6 invariances). This round cuts LDS instr per FLOP:
//  (1) global_load_lds staging for all bf16 operands (no ds_write instrs,
//      no reg round-trip) — rule #21: LINEAR LDS dest + XOR-pre-swizzled
//      SOURCE chunk; reader applies the same XOR (involution).
//  (2) MoE tiles 128x64 with acc[4][2]/wave: reads/MFMA 0.75 -> 0.5.
__device__ __forceinline__ int swz(int row, int e8) {
  return row * LDP + (e8 ^ (((row >> 1) & 3) << 3));
}

__device__ __forceinline__ void gload_lds16(const void* g, void* l) {
  __builtin_amdgcn_global_load_lds(
      (const __attribute__((address_space(1))) void*)g,
      (__attribute__((address_space(3))) void*)l, 16, 0, 0);
}

// x = h1 + h2 with h2 ~ eps*x (residual sub exact). Double-split: product
// error ~eps^2 — far below the MoE bf16 error floor (absmax 0.015625).
__device__ __forceinline__ void split2(float x, __bf16& h1, __bf16& h2) {
  h1 = (__bf16)x;
  h2 = (__bf16)(x - (float)h1);
}

// 3-combination double-split MFMA step: a1b1 + a1b2 + a2b1, error ~eps^2.
// Planes in LDS: A1 @0, A2 @PL, B1 @2PL, B2 @3PL.
__device__ __forceinline__ void mfma_step3(const __bf16* sm, int wr, int wc,
                                           int lm, int lq, f32x4 (&acc)[2][2]) {
  int ao0 = swz(wr + lm, lq * 8), ao1 = ao0 + 16 * LDP;  // (row+16) keeps swz bits
  int bo0 = swz(wc + lm, lq * 8), bo1 = bo0 + 16 * LDP;
  bf16x8 a10 = *(const bf16x8*)(sm + ao0),          a11 = *(const bf16x8*)(sm + ao1);
  bf16x8 a20 = *(const bf16x8*)(sm + PL + ao0),     a21 = *(const bf16x8*)(sm + PL + ao1);
  bf16x8 b10 = *(const bf16x8*)(sm + 2 * PL + bo0), b11 = *(const bf16x8*)(sm + 2 * PL + bo1);
  bf16x8 b20 = *(const bf16x8*)(sm + 3 * PL + bo0), b21 = *(const bf16x8*)(sm + 3 * PL + bo1);
#define MF(A, B, i, j) acc[i][j] = __builtin_amdgcn_mfma_f32_16x16x32_bf16(A, B, acc[i][j], 0, 0, 0)
  MF(a10, b10, 0, 0); MF(a10, b11, 0, 1); MF(a11, b10, 1, 0); MF(a11, b11, 1, 1);
  MF(a10, b20, 0, 0); MF(a10, b21, 0, 1); MF(a11, b20, 1, 0); MF(a11, b21, 1, 1);
  MF(a20, b10, 0, 0); MF(a20, b11, 0, 1); MF(a21, b10, 1, 0); MF(a21, b11, 1, 1);
#undef MF
}

__device__ __forceinline__ void cvt8(__bf16* dst, float4 f0, float4 f1) {
  __bf16 tmp[8] __attribute__((aligned(16))) = {
      (__bf16)f0.x, (__bf16)f0.y, (__bf16)f0.z, (__bf16)f0.w,
      (__bf16)f1.x, (__bf16)f1.y, (__bf16)f1.z, (__bf16)f1.w};
  *(int4*)dst = *(const int4*)tmp;
}

// ---------------- pre/post small kernels ----------------

__global__ __launch_bounds__(256) void split2_kernel(
    const float* __restrict__ src, __bf16* __restrict__ p1,
    __bf16* __restrict__ p2, int n) {
  int i = (blockIdx.x * 256 + threadIdx.x) * 4;
  if (i >= n) return;
  float4 v = *(const float4*)(src + i);
  __bf16 t1[4] __attribute__((aligned(8))), t2[4] __attribute__((aligned(8)));
  split2(v.x, t1[0], t2[0]);
  split2(v.y, t1[1], t2[1]);
  split2(v.z, t1[2], t2[2]);
  split2(v.w, t1[3], t2[3]);
  *(int2*)(p1 + i) = *(const int2*)t1;
  *(int2*)(p2 + i) = *(const int2*)t2;
}

__global__ __launch_bounds__(256) void rmsnorm_split2_kernel(
    const float* __restrict__ x, const float* __restrict__ w,
    __bf16* __restrict__ p1, __bf16* __restrict__ p2) {
  int row = blockIdx.x;
  const float* xr = x + (size_t)row * HID;
  float4 v = ((const float4*)xr)[threadIdx.x];
  float ss = v.x * v.x + v.y * v.y + v.z * v.z + v.w * v.w;
  for (int off = 32; off; off >>= 1) ss += __shfl_xor(ss, off);
  __shared__ float red[4];
  int lane = threadIdx.x & 63, wid = threadIdx.x >> 6;
  if (lane == 0) red[wid] = ss;
  __syncthreads();
  float tot = red[0] + red[1] + red[2] + red[3];
  float scale = rsqrtf(tot / (float)HID + RMS_EPS);
  float4 wv = ((const float4*)w)[threadIdx.x];
  float o[4] = {v.x * scale * wv.x, v.y * scale * wv.y,
                v.z * scale * wv.z, v.w * scale * wv.w};
  __bf16 t1[4] __attribute__((aligned(8))), t2[4] __attribute__((aligned(8)));
#pragma unroll
  for (int i = 0; i < 4; i++) split2(o[i], t1[i], t2[i]);
  size_t idx = (size_t)row * HID + threadIdx.x * 4;
  *(int2*)(p1 + idx) = *(const int2*)t1;
  *(int2*)(p2 + idx) = *(const int2*)t2;
}

__global__ __launch_bounds__(256) void rmsnorm_dual_kernel(
    const float* __restrict__ x, const float* __restrict__ w,
    float* __restrict__ outf, __bf16* __restrict__ outb) {
  int row = blockIdx.x;
  const float* xr = x + (size_t)row * HID;
  float4 v = ((const float4*)xr)[threadIdx.x];
  float ss = v.x * v.x + v.y * v.y + v.z * v.z + v.w * v.w;
  for (int off = 32; off; off >>= 1) ss += __shfl_xor(ss, off);
  __shared__ float red[4];
  int lane = threadIdx.x & 63, wid = threadIdx.x >> 6;
  if (lane == 0) red[wid] = ss;
  __syncthreads();
  float tot = red[0] + red[1] + red[2] + red[3];
  float scale = rsqrtf(tot / (float)HID + RMS_EPS);
  float4 wv = ((const float4*)w)[threadIdx.x];
  float o[4] = {v.x * scale * wv.x, v.y * scale * wv.y,
                v.z * scale * wv.z, v.w * scale * wv.w};
  size_t idx = (size_t)row * HID + threadIdx.x * 4;
  *(float4*)(outf + idx) = *(const float4*)o;
  __bf16 tb[4] __attribute__((aligned(8)));
#pragma unroll
  for (int i = 0; i < 4; i++) tb[i] = (__bf16)o[i];
  *(int2*)(outb + idx) = *(const int2*)tb;
}

__global__ __launch_bounds__(256) void rope_split_kernel(
    const float* __restrict__ qkv, const int* __restrict__ pos_ids,
    const float* __restrict__ qn_w, const float* __restrict__ kn_w,
    __bf16* __restrict__ qp1, __bf16* __restrict__ qp2,
    __bf16* __restrict__ kp1, __bf16* __restrict__ kp2,
    __bf16* __restrict__ vp1, __bf16* __restrict__ vp2) {
  int t = blockIdx.x;
  int b = t >> 10, s = t & 1023;
  int lane = threadIdx.x & 63, w = threadIdx.x >> 6;
  float pos = (float)pos_ids[t];
  int fi = lane & 31;
  float inv = powf(10000.0f, -((float)(2 * fi)) / 64.0f);
  float cs = cosf(pos * inv), sn = sinf(pos * inv);
  for (int i = 0; i < 6; i++) {
    int hh = w + 4 * i;  // 0-15 q heads, 16-19 k heads, 20-23 v heads
    float val = qkv[(size_t)t * QKV_N + hh * 64 + lane];
    __bf16 h1, h2;
    if (hh < 20) {
      float ss = val * val;
      for (int off = 32; off; off >>= 1) ss += __shfl_xor(ss, off);
      float scale = rsqrtf(ss / 64.0f + RMS_EPS);
      float wgt = (hh < 16) ? qn_w[lane] : kn_w[lane];
      val = val * scale * wgt;
      float partner = __shfl_xor(val, 32);
      float rot = (lane < 32) ? -partner : partner;
      val = val * cs + rot * sn;
      split2(val, h1, h2);
      if (hh < 16) {
        size_t idx = (((size_t)b * NHEAD + hh) * SEQ + s) * HDIM + lane;
        qp1[idx] = h1; qp2[idx] = h2;
      } else {
        size_t idx = (((size_t)b * NKV + (hh - 16)) * SEQ + s) * HDIM + lane;
        kp1[idx] = h1; kp2[idx] = h2;
      }
    } else {
      split2(val, h1, h2);
      size_t idx = (((size_t)b * NKV + (hh - 20)) * HDIM + lane) * SEQ + s;
      vp1[idx] = h1; vp2[idx] = h2;
    }
  }
}

// scores land as a single fp32 plane; softmax emits 2 bf16 planes for PV.
__global__ __launch_bounds__(256) void softmax2_kernel(
    const float* __restrict__ sf,
    __bf16* __restrict__ p1, __bf16* __restrict__ p2) {
  size_t roff = (size_t)blockIdx.x * SEQ;
  int tid = threadIdx.x;
  float4 v4 = *(const float4*)(sf + roff + tid * 4);
  float v[4] = {v4.x, v4.y, v4.z, v4.w};
  float mx = fmaxf(fmaxf(v[0], v[1]), fmaxf(v[2], v[3]));
  for (int off = 32; off; off >>= 1) mx = fmaxf(mx, __shfl_xor(mx, off));
  __shared__ float red[4], red2[4];
  int lane = tid & 63, wid = tid >> 6;
  if (lane == 0) red[wid] = mx;
  __syncthreads();
  mx = fmaxf(fmaxf(red[0], red[1]), fmaxf(red[2], red[3]));
  float e[4], sum = 0.f;
#pragma unroll
  for (int i = 0; i < 4; i++) { e[i] = expf(v[i] - mx); sum += e[i]; }
  for (int off = 32; off; off >>= 1) sum += __shfl_xor(sum, off);
  if (lane == 0) red2[wid] = sum;
  __syncthreads();
  sum = red2[0] + red2[1] + red2[2] + red2[3];
  float invs = 1.0f / sum;
  __bf16 t1[4] __attribute__((aligned(8))), t2[4] __attribute__((aligned(8)));
#pragma unroll
  for (int i = 0; i < 4; i++) split2(e[i] * invs, t1[i], t2[i]);
  *(int2*)(p1 + roff + tid * 4) = *(const int2*)t1;
  *(int2*)(p2 + roff + tid * 4) = *(const int2*)t2;
}

// ------------- double-split GEMMs (64x64 tile, BK=32) -------------
// All-bf16 operands staged via global_load_lds (linear dest, XOR-preswizzled
// source): no ds_write instrs, no staging regs. One barrier per k-step; the
// __syncthreads vmcnt drain doubles as the gld_lds completion wait (m97).

__global__ __launch_bounds__(256) void gemm_qkv4(
    const __bf16* __restrict__ a1, const __bf16* __restrict__ a2,
    const __bf16* __restrict__ b1, const __bf16* __restrict__ b2,
    float* __restrict__ qkv) {
  int m0 = blockIdx.x * 64, n0 = blockIdx.y * 64;
  __shared__ __bf16 sm[2][4 * PL];  // 32 KB
  int tid = threadIdx.x, r = tid >> 2;
  int csw = ((tid & 3) ^ ((r >> 1) & 3)) * 8;  // pre-swizzled source chunk
  size_t aoff = (size_t)(m0 + r) * HID + csw, boff = (size_t)(n0 + r) * HID + csw;
  f32x4 acc[2][2] = {};
  int lane = tid & 63, wid = tid >> 6;
  int wr = (wid >> 1) * 32, wc = (wid & 1) * 32, lq = lane >> 4, lm = lane & 15;
  auto gld4 = [&](int p, int k0) {
    gload_lds16(a1 + aoff + k0, &sm[p][0 * PL + tid * 8]);
    gload_lds16(a2 + aoff + k0, &sm[p][1 * PL + tid * 8]);
    gload_lds16(b1 + boff + k0, &sm[p][2 * PL + tid * 8]);
    gload_lds16(b2 + boff + k0, &sm[p][3 * PL + tid * 8]);
  };
  gld4(0, 0);
  __syncthreads();
  int p = 0;
  for (int k0 = 0; k0 < HID; k0 += 32, p ^= 1) {
    if (k0 + 32 < HID) gld4(p ^ 1, k0 + 32);
    mfma_step3(sm[p], wr, wc, lm, lq, acc);
    __syncthreads();
  }
#pragma unroll
  for (int mt = 0; mt < 2; mt++)
#pragma unroll
    for (int nt = 0; nt < 2; nt++)
#pragma unroll
      for (int i = 0; i < 4; i++) {
        int gm = m0 + wr + mt * 16 + lq * 4 + i;
        int gc = n0 + wc + nt * 16 + lm;
        qkv[(size_t)gm * QKV_N + gc] = acc[mt][nt][i];
      }
}

__global__ __launch_bounds__(256) void gemm_scores4(
    const __bf16* __restrict__ qp1, const __bf16* __restrict__ qp2,
    const __bf16* __restrict__ kp1, const __bf16* __restrict__ kp2,
    float* __restrict__ sf, int b, int h0) {
  int hz = blockIdx.z, h = h0 + hz;
  int m0 = blockIdx.x * 64, n0 = blockIdx.y * 64;
  size_t qbase = ((size_t)(b * NHEAD + h)) * SEQ * HDIM;
  size_t kbase = ((size_t)(b * NKV + (h >> 2))) * SEQ * HDIM;
  __shared__ __bf16 sm[2][4 * PL];
  int tid = threadIdx.x, r = tid >> 2;
  int csw = ((tid & 3) ^ ((r >> 1) & 3)) * 8;
  size_t aoff = qbase + (size_t)(m0 + r) * HDIM + csw;
  size_t boff = kbase + (size_t)(n0 + r) * HDIM + csw;
  f32x4 acc[2][2] = {};
  int lane = tid & 63, wid = tid >> 6;
  int wr = (wid >> 1) * 32, wc = (wid & 1) * 32, lq = lane >> 4, lm = lane & 15;
  auto gld4 = [&](int p, int k0) {
    gload_lds16(qp1 + aoff + k0, &sm[p][0 * PL + tid * 8]);
    gload_lds16(qp2 + aoff + k0, &sm[p][1 * PL + tid * 8]);
    gload_lds16(kp1 + boff + k0, &sm[p][2 * PL + tid * 8]);
    gload_lds16(kp2 + boff + k0, &sm[p][3 * PL + tid * 8]);
  };
  gld4(0, 0);
  __syncthreads();
  int p = 0;
  for (int k0 = 0; k0 < HDIM; k0 += 32, p ^= 1) {
    if (k0 + 32 < HDIM) gld4(p ^ 1, k0 + 32);
    mfma_step3(sm[p], wr, wc, lm, lq, acc);
    __syncthreads();
  }
#pragma unroll
  for (int mt = 0; mt < 2; mt++)
#pragma unroll
    for (int nt = 0; nt < 2; nt++)
#pragma unroll
      for (int i = 0; i < 4; i++) {
        int gm = m0 + wr + mt * 16 + lq * 4 + i;
        int gc = n0 + wc + nt * 16 + lm;
        size_t idx = ((size_t)hz * SEQ + gm) * SEQ + gc;
        sf[idx] = acc[mt][nt][i] * 0.125f;
      }
}

__global__ __launch_bounds__(256) void gemm_pv4(
    const __bf16* __restrict__ s1, const __bf16* __restrict__ s2,
    const __bf16* __restrict__ vp1, const __bf16* __restrict__ vp2,
    __bf16* __restrict__ o1, __bf16* __restrict__ o2,
    int b, int h0) {
  int hz = blockIdx.z, h = h0 + hz;
  int m0 = blockIdx.x * 64;
  size_t pbase = (size_t)hz * SEQ * SEQ;
  size_t vbase = ((size_t)(b * NKV + (h >> 2))) * HDIM * SEQ;
  __shared__ __bf16 sm[2][4 * PL];  // 32 KB
  int tid = threadIdx.x, r = tid >> 2;
  int csw = ((tid & 3) ^ ((r >> 1) & 3)) * 8;
  size_t aoff = pbase + (size_t)(m0 + r) * SEQ + csw;
  size_t boff = vbase + (size_t)r * SEQ + csw;
  f32x4 acc[2][2] = {};
  int lane = tid & 63, wid = tid >> 6;
  int wr = (wid >> 1) * 32, wc = (wid & 1) * 32, lq = lane >> 4, lm = lane & 15;
  auto gld4 = [&](int p, int k0) {
    gload_lds16(s1 + aoff + k0, &sm[p][0 * PL + tid * 8]);
    gload_lds16(s2 + aoff + k0, &sm[p][1 * PL + tid * 8]);
    gload_lds16(vp1 + boff + k0, &sm[p][2 * PL + tid * 8]);
    gload_lds16(vp2 + boff + k0, &sm[p][3 * PL + tid * 8]);
  };
  gld4(0, 0);
  __syncthreads();
  int p = 0;
  for (int k0 = 0; k0 < SEQ; k0 += 32, p ^= 1) {
    if (k0 + 32 < SEQ) gld4(p ^ 1, k0 + 32);
    mfma_step3(sm[p], wr, wc, lm, lq, acc);
    __syncthreads();
  }
#pragma unroll
  for (int mt = 0; mt < 2; mt++)
#pragma unroll
    for (int nt = 0; nt < 2; nt++)
#pragma unroll
      for (int i = 0; i < 4; i++) {
        int gm = m0 + wr + mt * 16 + lq * 4 + i;
        int gc = wc + nt * 16 + lm;
        size_t idx = ((size_t)(b * SEQ + gm)) * HID + h * 64 + gc;
        __bf16 h1_, h2_;
        split2(acc[mt][nt][i], h1_, h2_);
        o1[idx] = h1_; o2[idx] = h2_;
      }
}

__global__ __launch_bounds__(256) void gemm_oproj4(
    const __bf16* __restrict__ a1, const __bf16* __restrict__ a2,
    const __bf16* __restrict__ b1, const __bf16* __restrict__ b2,
    const float* __restrict__ hidden, float* __restrict__ x1, float* __restrict__ outp) {
  int m0 = blockIdx.x * 64, n0 = blockIdx.y * 64;
  __shared__ __bf16 sm[2][4 * PL];  // 32 KB
  int tid = threadIdx.x, r = tid >> 2;
  int csw = ((tid & 3) ^ ((r >> 1) & 3)) * 8;
  size_t aoff = (size_t)(m0 + r) * HID + csw, boff = (size_t)(n0 + r) * HID + csw;
  f32x4 acc[2][2] = {};
  int lane = tid & 63, wid = tid >> 6;
  int wr = (wid >> 1) * 32, wc = (wid & 1) * 32, lq = lane >> 4, lm = lane & 15;
  auto gld4 = [&](int p, int k0) {
    gload_lds16(a1 + aoff + k0, &sm[p][0 * PL + tid * 8]);
    gload_lds16(a2 + aoff + k0, &sm[p][1 * PL + tid * 8]);
    gload_lds16(b1 + boff + k0, &sm[p][2 * PL + tid * 8]);
    gload_lds16(b2 + boff + k0, &sm[p][3 * PL + tid * 8]);
  };
  gld4(0, 0);
  __syncthreads();
  int p = 0;
  for (int k0 = 0; k0 < HID; k0 += 32, p ^= 1) {
    if (k0 + 32 < HID) gld4(p ^ 1, k0 + 32);
    mfma_step3(sm[p], wr, wc, lm, lq, acc);
    __syncthreads();
  }
#pragma unroll
  for (int mt = 0; mt < 2; mt++)
#pragma unroll
    for (int nt = 0; nt < 2; nt++)
#pragma unroll
      for (int i = 0; i < 4; i++) {
        int gm = m0 + wr + mt * 16 + lq * 4 + i;
        int gc = n0 + wc + nt * 16 + lm;
        size_t idx = (size_t)gm * HID + gc;
        float val = hidden[idx] + acc[mt][nt][i];
        x1[idx] = val;
        outp[idx] = val;
      }
}

// ---------------- MoE ----------------

__global__ void zero_cnt_kernel(int* cnt) {
  if (threadIdx.x < NEXP) cnt[threadIdx.x] = 0;
}

__global__ __launch_bounds__(64) void gating_kernel(
    const float* __restrict__ h2f, const float* __restrict__ gw,
    float* __restrict__ logits_out, int* __restrict__ cnt,
    int* __restrict__ list, float* __restrict__ wt) {
  int t = blockIdx.x;
  int lane = threadIdx.x;
  const float* xr = h2f + (size_t)t * HID;
  float part[NEXP] = {};
  for (int k = lane; k < HID; k += 64) {
    float xv = xr[k];
#pragma unroll
    for (int e = 0; e < NEXP; e++) part[e] += xv * gw[e * HID + k];
  }
#pragma unroll
  for (int e = 0; e < NEXP; e++)
    for (int off = 32; off; off >>= 1) part[e] += __shfl_xor(part[e], off);
  if (lane < NEXP) logits_out[(size_t)t * NEXP + lane] = part[lane];
  float mx = part[0];
#pragma unroll
  for (int e = 1; e < NEXP; e++) mx = fmaxf(mx, part[e]);
  float pe[NEXP];
#pragma unroll
  for (int e = 0; e < NEXP; e++) pe[e] = expf(part[e] - mx);
  int e0 = 0; float p0 = pe[0];
#pragma unroll
  for (int e = 1; e < NEXP; e++) if (pe[e] > p0) { p0 = pe[e]; e0 = e; }
  int e1 = -1; float p1 = -1.f;
#pragma unroll
  for (int e = 0; e < NEXP; e++) if (e != e0 && pe[e] > p1) { p1 = pe[e]; e1 = e; }
  float wsum = p0 + p1;
  if (lane == 0) {
    int pos0 = atomicAdd(&cnt[e0], 1);
    list[e0 * TOK + pos0] = t;
    wt[e0 * TOK + pos0] = p0 / wsum;
    int pos1 = atomicAdd(&cnt[e1], 1);
    list[e1 * TOK + pos1] = t;
    wt[e1 * TOK + pos1] = p1 / wsum;
  }
}

// scan + dense 128-row block table (all-CU coverage, round-5).
__global__ void scan_kernel(const int* __restrict__ cnt, int* __restrict__ base,
                            int* __restrict__ btab, int* __restrict__ nblk) {
  if (threadIdx.x == 0 && blockIdx.x == 0) {
    int acc = 0, nb = 0;
    for (int e = 0; e < NEXP; e++) {
      base[e] = acc; acc += cnt[e];
      for (int m0 = 0; m0 < cnt[e]; m0 += 128) {
        btab[2 * nb] = e; btab[2 * nb + 1] = m0; nb++;
      }
    }
    base[NEXP] = acc;
    *nblk = nb;
  }
}

// fused gate+up, 128(M)x64(N), BK=32, acc[4][2] per wave (0.5 LDS reads/MFMA),
// A via gld_lds (2 instr/thread), fp32 weights reg-staged 1-deep + cvt.
// LDS instr/FLOP cut ~2.2x vs round-7. grid (FFD/64, MAXBLK) over btab.
__global__ __launch_bounds__(256) void gemm_gateup3(
    const __bf16* __restrict__ h2, const float* __restrict__ w_gate,
    const float* __restrict__ w_up, const int* __restrict__ cnt,
    const int* __restrict__ base, const int* __restrict__ list,
    const int* __restrict__ btab, const int* __restrict__ nblk,
    __bf16* __restrict__ aws) {
  int slot = blockIdx.y;
  if (slot >= *nblk) return;
  int e = btab[2 * slot], m0 = btab[2 * slot + 1];
  int ce = cnt[e];
  int n0 = blockIdx.x * 64;
  int be = base[e];
  __shared__ __bf16 As[2][128 * LDP], Bg[2][PL], Bu[2][PL];  // 16+8+8 = 32 KB
  int tid = threadIdx.x, r = tid >> 2, c8 = (tid & 3) * 8;
  int csw = ((tid & 3) ^ ((r >> 1) & 3)) * 8;  // gld_lds source pre-swizzle
  int rx0 = m0 + r;      if (rx0 >= ce) rx0 = ce - 1;
  int rx1 = m0 + 64 + r; if (rx1 >= ce) rx1 = ce - 1;  // b(row+64)==b(row): same csw
  const __bf16* arow0 = h2 + (size_t)list[e * TOK + rx0] * HID + csw;
  const __bf16* arow1 = h2 + (size_t)list[e * TOK + rx1] * HID + csw;
  const float* bgrow = w_gate + ((size_t)e * FFD + n0 + r) * HID + c8;
  const float* burow = w_up + ((size_t)e * FFD + n0 + r) * HID + c8;
  int lane = tid & 63, wid = tid >> 6;
  int wr = (wid >> 1) * 64, wc = (wid & 1) * 32, lq = lane >> 4, lm = lane & 15;
  int sidx = swz(r, c8);
  f32x4 ag[4][2] = {}, au[4][2] = {};
  float4 rg0, rg1, ru0, ru1;
  auto gldA = [&](int p, int k0) {
    gload_lds16(arow0 + k0, &As[p][tid * 8]);
    gload_lds16(arow1 + k0, &As[p][2048 + tid * 8]);
  };
  auto preloadB = [&](int k0) {
    rg0 = *(const float4*)(bgrow + k0); rg1 = *(const float4*)(bgrow + k0 + 4);
    ru0 = *(const float4*)(burow + k0); ru1 = *(const float4*)(burow + k0 + 4);
  };
  auto stageB = [&](int p) {
    cvt8(&Bg[p][sidx], rg0, rg1);
    cvt8(&Bu[p][sidx], ru0, ru1);
  };
  auto compute = [&](int p) {
    int bo0 = swz(wc + lm, lq * 8), bo1 = bo0 + 16 * LDP;
    bf16x8 g0 = *(const bf16x8*)(&Bg[p][bo0]);
    bf16x8 g1 = *(const bf16x8*)(&Bg[p][bo1]);
    bf16x8 u0 = *(const bf16x8*)(&Bu[p][bo0]);
    bf16x8 u1 = *(const bf16x8*)(&Bu[p][bo1]);
#pragma unroll
    for (int mt = 0; mt < 4; mt++) {
      bf16x8 a = *(const bf16x8*)(&As[p][swz(wr + mt * 16 + lm, lq * 8)]);
      ag[mt][0] = __builtin_amdgcn_mfma_f32_16x16x32_bf16(a, g0, ag[mt][0], 0, 0, 0);
      ag[mt][1] = __builtin_amdgcn_mfma_f32_16x16x32_bf16(a, g1, ag[mt][1], 0, 0, 0);
      au[mt][0] = __builtin_amdgcn_mfma_f32_16x16x32_bf16(a, u0, au[mt][0], 0, 0, 0);
      au[mt][1] = __builtin_amdgcn_mfma_f32_16x16x32_bf16(a, u1, au[mt][1], 0, 0, 0);
    }
  };
  preloadB(0);
  gldA(0, 0);
  stageB(0);
  preloadB(32);
  __syncthreads();
  int p = 0;
  for (int k0 = 0; k0 < HID; k0 += 32, p ^= 1) {
    if (k0 + 32 < HID) {
      gldA(p ^ 1, k0 + 32);
      stageB(p ^ 1);                         // regs from previous iter's preload
      preloadB(k0 + 64 < HID ? k0 + 64 : 0); // 1-deep ahead
    }
    compute(p);
    __syncthreads();
  }
#pragma unroll
  for (int mt = 0; mt < 4; mt++)
#pragma unroll
    for (int nt = 0; nt < 2; nt++)
#pragma unroll
      for (int i = 0; i < 4; i++) {
        int lrow = m0 + wr + mt * 16 + lq * 4 + i;
        if (lrow < ce) {
          int gc = n0 + wc + nt * 16 + lm;
          float g = ag[mt][nt][i], u = au[mt][nt][i];
          float a = g / (1.0f + expf(-g)) * u;
          aws[((size_t)(be + lrow)) * FFD + gc] = (__bf16)a;
        }
      }
}

// down GEMM, 128(M)x64(N), acc[4][2]; A via gld_lds, fp32 w_down reg-staged;
// weighted atomic scatter. grid (HID/64, MAXBLK).
__global__ __launch_bounds__(256) void gemm_down3(
    const __bf16* __restrict__ aws, const float* __restrict__ w_down,
    const int* __restrict__ cnt, const int* __restrict__ base,
    const int* __restrict__ list, const float* __restrict__ wt,
    const int* __restrict__ btab, const int* __restrict__ nblk,
    float* __restrict__ outp) {
  int slot = blockIdx.y;
  if (slot >= *nblk) return;
  int e = btab[2 * slot], m0 = btab[2 * slot + 1];
  int ce = cnt[e];
  int n0 = blockIdx.x * 64;
  int be = base[e];
  __shared__ __bf16 As[2][128 * LDP], Bs[2][PL];  // 16+8 = 24 KB
  int tid = threadIdx.x, r = tid >> 2, c8 = (tid & 3) * 8;
  int csw = ((tid & 3) ^ ((r >> 1) & 3)) * 8;
  int rx0 = m0 + r;      if (rx0 >= ce) rx0 = ce - 1;
  int rx1 = m0 + 64 + r; if (rx1 >= ce) rx1 = ce - 1;
  const __bf16* arow0 = aws + (size_t)(be + rx0) * FFD + csw;
  const __bf16* arow1 = aws + (size_t)(be + rx1) * FFD + csw;
  const float* brow = w_down + ((size_t)e * HID + n0 + r) * FFD + c8;
  int lane = tid & 63, wid = tid >> 6;
  int wr = (wid >> 1) * 64, wc = (wid & 1) * 32, lq = lane >> 4, lm = lane & 15;
  int sidx = swz(r, c8);
  f32x4 acc[4][2] = {};
  float4 rb0, rb1;
  auto gldA = [&](int p, int k0) {
    gload_lds16(arow0 + k0, &As[p][tid * 8]);
    gload_lds16(arow1 + k0, &As[p][2048 + tid * 8]);
  };
  auto preloadB = [&](int k0) {
    rb0 = *(const float4*)(brow + k0); rb1 = *(const float4*)(brow + k0 + 4);
  };
  auto stageB = [&](int p) { cvt8(&Bs[p][sidx], rb0, rb1); };
  auto compute = [&](int p) {
    int bo0 = swz(wc + lm, lq * 8), bo1 = bo0 + 16 * LDP;
    bf16x8 b0 = *(const bf16x8*)(&Bs[p][bo0]);
    bf16x8 b1 = *(const bf16x8*)(&Bs[p][bo1]);
#pragma unroll
    for (int mt = 0; mt < 4; mt++) {
      bf16x8 a = *(const bf16x8*)(&As[p][swz(wr + mt * 16 + lm, lq * 8)]);
      acc[mt][0] = __builtin_amdgcn_mfma_f32_16x16x32_bf16(a, b0, acc[mt][0], 0, 0, 0);
      acc[mt][1] = __builtin_amdgcn_mfma_f32_16x16x32_bf16(a, b1, acc[mt][1], 0, 0, 0);
    }
  };
  preloadB(0);
  gldA(0, 0);
  stageB(0);
  preloadB(32);
  __syncthreads();
  int p = 0;
  for (int k0 = 0; k0 < FFD; k0 += 32, p ^= 1) {
    if (k0 + 32 < FFD) {
      gldA(p ^ 1, k0 + 32);
      stageB(p ^ 1);
      preloadB(k0 + 64 < FFD ? k0 + 64 : 0);
    }
    compute(p);
    __syncthreads();
  }
#pragma unroll
  for (int mt = 0; mt < 4; mt++)
#pragma unroll
    for (int nt = 0; nt < 2; nt++)
#pragma unroll
      for (int i = 0; i < 4; i++) {
        int lrow = m0 + wr + mt * 16 + lq * 4 + i;
        if (lrow < ce) {
          int gc = n0 + wc + nt * 16 + lm;
          int tok = list[e * TOK + lrow];
          float wgt = wt[e * TOK + lrow];
          atomicAdd(&outp[(size_t)tok * HID + gc], wgt * acc[mt][nt][i]);
        }
      }
}

// ---------------- launcher ----------------

extern "C" void kernel_launch(void* const* d_in, const int* in_sizes, int n_in,
                              void* d_out, int out_size, void* d_ws, size_t ws_size,
                              hipStream_t stream) {
  const float* hidden = (const float*)d_in[0];
  const int* pos_ids = (const int*)d_in[1];
  const float* ln1_w = (const float*)d_in[2];
  const float* ln2_w = (const float*)d_in[3];
  const float* q_w = (const float*)d_in[4];
  const float* k_w = (const float*)d_in[5];
  const float* v_w = (const float*)d_in[6];
  const float* o_w = (const float*)d_in[7];
  const float* qn_w = (const float*)d_in[8];
  const float* kn_w = (const float*)d_in[9];
  const float* gate_w = (const float*)d_in[10];
  const float* w_gate = (const float*)d_in[11];
  const float* w_up = (const float*)d_in[12];
  const float* w_down = (const float*)d_in[13];
  float* outp = (float*)d_out;
  float* logits_out = outp + (size_t)TOK * HID;

  char* ws = (char*)d_ws;
  size_t off = 0;
  auto alloc = [&](size_t bytes) {
    void* p = ws + off;
    off += (bytes + 255) & ~(size_t)255;
    return p;
  };
  const size_t NWQ = (size_t)QKV_N * HID, NOW = (size_t)HID * HID;
  __bf16* wqp1 = (__bf16*)alloc(NWQ * 2); __bf16* wqp2 = (__bf16*)alloc(NWQ * 2);
  __bf16* owp1 = (__bf16*)alloc(NOW * 2); __bf16* owp2 = (__bf16*)alloc(NOW * 2);
  const size_t NH1 = (size_t)TOK * HID;
  __bf16* h1p1 = (__bf16*)alloc(NH1 * 2); __bf16* h1p2 = (__bf16*)alloc(NH1 * 2);
  float* qkvf = (float*)alloc((size_t)TOK * QKV_N * 4);
  const size_t NQ = (size_t)NB * NHEAD * SEQ * HDIM, NK = (size_t)NB * NKV * SEQ * HDIM;
  __bf16* qp1 = (__bf16*)alloc(NQ * 2); __bf16* qp2 = (__bf16*)alloc(NQ * 2);
  __bf16* kp1 = (__bf16*)alloc(NK * 2); __bf16* kp2 = (__bf16*)alloc(NK * 2);
  __bf16* vp1 = (__bf16*)alloc(NK * 2); __bf16* vp2 = (__bf16*)alloc(NK * 2);
  // score storage per hch chunk: fp32 plane (4B) + 2 bf16 softmax planes (4B).
  size_t fixed_rest = NH1 * 2 * 2 /*op*/ + NH1 * 4 * 2 /*x1,h2f*/ + NH1 * 2 /*h2b*/ +
                      NEXP * 4 * 2 + (size_t)NEXP * TOK * 8 +
                      (size_t)TOK * 2 * FFD * 2 + (1 << 20);
  size_t avail = (ws_size > off + fixed_rest) ? (ws_size - off - fixed_rest) : 0;
  int hch = (avail >= (size_t)16 * SEQ * SEQ * 8) ? 16 : 8;
  const size_t NP = (size_t)hch * SEQ * SEQ;
  float* spf = (float*)alloc(NP * 4);
  __bf16* sp1 = (__bf16*)alloc(NP * 2); __bf16* sp2 = (__bf16*)alloc(NP * 2);
  __bf16* op1 = (__bf16*)alloc(NH1 * 2); __bf16* op2 = (__bf16*)alloc(NH1 * 2);
  float* x1 = (float*)alloc(NH1 * 4);
  float* h2f = (float*)alloc(NH1 * 4);
  __bf16* h2b = (__bf16*)alloc(NH1 * 2);
  int* cnt = (int*)alloc(NEXP * 4);
  int* base = (int*)alloc((NEXP + 1) * 4);
  int* list = (int*)alloc((size_t)NEXP * TOK * 4);
  float* wt = (float*)alloc((size_t)NEXP * TOK * 4);
  int* btab = (int*)alloc((size_t)MAXBLK * 2 * 4);
  int* nblk = (int*)alloc(4);
  __bf16* aws = (__bf16*)alloc((size_t)TOK * 2 * FFD * 2);
  (void)in_sizes; (void)n_in; (void)out_size;

  // weight splits
  split2_kernel<<<1024, 256, 0, stream>>>(q_w, wqp1, wqp2, 1024 * 1024);
  split2_kernel<<<256, 256, 0, stream>>>(k_w, wqp1 + 1024 * 1024, wqp2 + 1024 * 1024,
                                         256 * 1024);
  split2_kernel<<<256, 256, 0, stream>>>(v_w, wqp1 + 1280 * 1024, wqp2 + 1280 * 1024,
                                         256 * 1024);
  split2_kernel<<<1024, 256, 0, stream>>>(o_w, owp1, owp2, 1024 * 1024);

  // attention (double-split MFMA: error ~eps^2, far below MoE bf16 floor)
  rmsnorm_split2_kernel<<<TOK, 256, 0, stream>>>(hidden, ln1_w, h1p1, h1p2);
  gemm_qkv4<<<dim3(TOK / 64, QKV_N / 64), 256, 0, stream>>>(
      h1p1, h1p2, wqp1, wqp2, qkvf);
  rope_split_kernel<<<TOK, 256, 0, stream>>>(qkvf, pos_ids, qn_w, kn_w,
                                             qp1, qp2, kp1, kp2, vp1, vp2);
  for (int b = 0; b < NB; b++)
    for (int hc = 0; hc < NHEAD / hch; hc++) {
      int h0 = hc * hch;
      gemm_scores4<<<dim3(SEQ / 64, SEQ / 64, hch), 256, 0, stream>>>(
          qp1, qp2, kp1, kp2, spf, b, h0);
      softmax2_kernel<<<hch * SEQ, 256, 0, stream>>>(spf, sp1, sp2);
      gemm_pv4<<<dim3(SEQ / 64, 1, hch), 256, 0, stream>>>(
          sp1, sp2, vp1, vp2, op1, op2, b, h0);
    }
  gemm_oproj4<<<dim3(TOK / 64, HID / 64), 256, 0, stream>>>(
      op1, op2, owp1, owp2, hidden, x1, outp);

  // MoE
  rmsnorm_dual_kernel<<<TOK, 256, 0, stream>>>(x1, ln2_w, h2f, h2b);
  zero_cnt_kernel<<<1, 64, 0, stream>>>(cnt);
  gating_kernel<<<TOK, 64, 0, stream>>>(h2f, gate_w, logits_out, cnt, list, wt);
  scan_kernel<<<1, 1, 0, stream>>>(cnt, base, btab, nblk);
  gemm_gateup3<<<dim3(FFD / 64, MAXBLK), 256, 0, stream>>>(
      h2b, w_gate, w_up, cnt, base, list, btab, nblk, aws);
  gemm_down3<<<dim3(HID / 64, MAXBLK), 256, 0, stream>>>(
      aws, w_down, cnt, base, list, wt, btab, nblk, outp);
}